// Round 12
// baseline (211.576 us; speedup 1.0000x reference)
//
#include <hip/hip_runtime.h>
#include <stdint.h>

// ---------------- problem constants (hard-coded from reference) ----------------
#define B_    2
#define N_    1000
#define C_    256
#define H_    50
#define W_    50
#define P_    7
#define NCLS  91
#define REP_  1024
#define DIN   (C_ * P_ * P_)   // 12544
#define M_    (B_ * N_)        // 2000
#define MPAD  2048
#define HOUT  512              // padded head cols (91 cls + 364 bbox = 455 real)
#define DET_  100
#define NMSM  (N_ * 90)        // 90000 candidates per batch
#define NEGV  (-1000000000.0f)
#define SCALE_ 0.0625f
#define IMGF  800.0f
#define BBOX_CLIPF 4.135166556742356f  // log(1000/16)

#define RC_   25               // rois per roi-chunk (1000 % 25 == 0: no batch mixing)
#define CC_   4                // channels per channel-chunk

typedef __bf16 bf16_t;
typedef __attribute__((ext_vector_type(8))) __bf16 bf16x8;
typedef __attribute__((ext_vector_type(4))) __bf16 bf16x4;
typedef __attribute__((ext_vector_type(4))) float f32x4;

// async global->LDS, 16B per lane. LDS dest must be wave-uniform base (+lane*16 by HW).
__device__ __forceinline__ void gload16(const void* g, void* l) {
  auto gp = (const __attribute__((address_space(1))) uint32_t*)(uintptr_t)g;
  auto lp = (__attribute__((address_space(3))) uint32_t*)(uint32_t)(uintptr_t)l;
  __builtin_amdgcn_global_load_lds(gp, lp, 16, 0, 0);
}

// ---------------- ROI align: LDS-staged feature planes, paired ds_read2 gathers ----------------
__global__ __launch_bounds__(256) void roi_kernel(const float* __restrict__ features,
                                                  const float* __restrict__ proposals,
                                                  bf16_t* __restrict__ A) {
  const int cc0 = blockIdx.x * CC_;       // channel base (0..252)
  const int roiBase = blockIdx.y * RC_;   // roi base
  const int t = threadIdx.x;
  if (roiBase >= M_) {
    for (int idx = t; idx < RC_ * 49; idx += 256) {
      const int r = idx / 49, pp = idx - r * 49;
      const int n = roiBase + r;
      if (n < MPAD) {
        bf16_t* arow = A + (size_t)n * DIN + cc0 * 49 + pp;
#pragma unroll
        for (int c = 0; c < CC_; ++c) arow[c * 49] = (bf16_t)0.0f;
      }
    }
    return;
  }
  __shared__ __align__(16) float s_pl[CC_ * 2500];   // 40000 B
  __shared__ float s_ly[RC_ * 49];
  __shared__ float s_lx[RC_ * 49];
  __shared__ unsigned short s_off[RC_ * 49];
  const int b = (roiBase >= N_) ? 1 : 0;
  const f32x4* src = (const f32x4*)(features + (size_t)(b * C_ + cc0) * (H_ * W_));
  f32x4* dst = (f32x4*)s_pl;
  for (int i = t; i < CC_ * 2500 / 4; i += 256) dst[i] = src[i];
  for (int idx = t; idx < RC_ * 49; idx += 256) {
    const int r = idx / 49, pp = idx - r * 49;
    const int py = pp / 7, px = pp - py * 7;
    const float* p = proposals + (roiBase + r) * 4;
    float y1 = p[1] * SCALE_, y2 = p[3] * SCALE_;
    float bh = (y2 - y1) * (1.0f / 7.0f);
    float y = y1 + ((float)py + 0.5f) * bh - 0.5f;
    y = fminf(fmaxf(y, 0.0f), 49.0f);
    int y0 = (int)floorf(y);
    int dy = (y0 < 49) ? 1 : 0;
    float ly = y - (float)y0;
    float x1 = p[0] * SCALE_, x2 = p[2] * SCALE_;
    float bw = (x2 - x1) * (1.0f / 7.0f);
    float x = x1 + ((float)px + 0.5f) * bw - 0.5f;
    x = fminf(fmaxf(x, 0.0f), 49.0f);
    int x0 = (int)floorf(x);
    int dx = (x0 < 49) ? 1 : 0;
    float lx = x - (float)x0;
    s_off[idx] = (unsigned short)((y0 * W_ + x0) | (dx << 12) | (dy << 13));
    s_ly[idx] = ly;
    s_lx[idx] = lx;
  }
  __syncthreads();
  for (int idx = t; idx < RC_ * 49; idx += 256) {
    const int r = idx / 49, pp = idx - r * 49;
    const unsigned off = s_off[idx];
    const float ly = s_ly[idx], lx = s_lx[idx];
    const float hy = 1.0f - ly, hx = 1.0f - lx;
    const int o00 = off & 0xFFF;
    const int dx = (off >> 12) & 1;
    const int o10 = o00 + W_ * ((off >> 13) & 1);
    const float w00 = hy * hx, w01 = hy * lx, w10 = ly * hx, w11 = ly * lx;
    bf16_t* arow = A + (size_t)(roiBase + r) * DIN + cc0 * 49 + pp;
#pragma unroll
    for (int c = 0; c < CC_; ++c) {
      const float* pl = s_pl + c * 2500;
      float a0 = pl[o00], a1 = pl[o00 + 1];
      float b0v = pl[o10], b1v = pl[o10 + 1];
      float ax = dx ? a1 : a0;
      float bx = dx ? b1v : b0v;
      float v = a0 * w00 + ax * w01 + b0v * w10 + bx * w11;
      arow[c * 49] = (bf16_t)v;
    }
  }
}

// ---------------- fused prep: w1^T, w2^T (f32->bf16 transpose), head weight/bias ----------------
#define NW1B  ((DIN / 32) * (REP_ / 32))    // 12544
#define NW2B  ((REP_ / 32) * (REP_ / 32))   // 1024
#define NHWB  ((HOUT * REP_) / 256)         // 2048
__global__ __launch_bounds__(256) void prep_kernel(const float* __restrict__ w1,
                                                   const float* __restrict__ w2,
                                                   const float* __restrict__ wcls,
                                                   const float* __restrict__ wbb,
                                                   const float* __restrict__ bcls,
                                                   const float* __restrict__ bbb,
                                                   bf16_t* __restrict__ w1t,
                                                   bf16_t* __restrict__ w2t,
                                                   bf16_t* __restrict__ wht,
                                                   float* __restrict__ biash) {
  __shared__ float tile[32][33];
  int bidx = blockIdx.x;
  if (bidx < NW1B + NW2B) {
    const float* in;
    bf16_t* out;
    int K, N, kb, nb;
    if (bidx < NW1B) {
      in = w1; out = w1t; K = DIN; N = REP_;
      kb = bidx % (DIN / 32); nb = bidx / (DIN / 32);
    } else {
      bidx -= NW1B;
      in = w2; out = w2t; K = REP_; N = REP_;
      kb = bidx % (REP_ / 32); nb = bidx / (REP_ / 32);
    }
    const int k0 = kb * 32, n0 = nb * 32;
    const int tx = threadIdx.x & 31;
    const int ty = threadIdx.x >> 5;
#pragma unroll
    for (int j = 0; j < 4; ++j) {
      int ky = ty + j * 8;
      tile[ky][tx] = in[(size_t)(k0 + ky) * N + n0 + tx];
    }
    __syncthreads();
    const int qx = threadIdx.x & 7;
    const int ny = threadIdx.x >> 3;
    bf16x4 o;
#pragma unroll
    for (int i = 0; i < 4; ++i) o[i] = (bf16_t)tile[4 * qx + i][ny];
    *(bf16x4*)(&out[(size_t)(n0 + ny) * K + k0 + 4 * qx]) = o;
  } else if (bidx < NW1B + NW2B + NHWB) {
    int idx = (bidx - NW1B - NW2B) * 256 + threadIdx.x;
    int j = idx >> 10;
    int k = idx & 1023;
    float v = 0.0f;
    if (j < NCLS) v = wcls[(size_t)k * NCLS + j];
    else if (j < 455) v = wbb[(size_t)k * 364 + (j - NCLS)];
    wht[idx] = (bf16_t)v;
  } else {
    for (int j = threadIdx.x; j < HOUT; j += 256) {
      float v = 0.0f;
      if (j < NCLS) v = bcls[j];
      else if (j < 455) v = bbb[j - NCLS];
      biash[j] = v;
    }
  }
}

// ---------------- 256x256-tile deep-pipelined MFMA GEMM (8-wave) ----------------
// R9-proven schedule: stage(kt g+3) FIRST -> one-shot frag reads -> lgkm(0)/counted
// vmcnt -> single barrier -> MFMA cluster. 4 LDS buffers (128 KiB), depth-3 prefetch,
// st_16x32 swizzle both-sides, zc = bid % KC pins each K-chunk to one XCD.
// Requires G = kLen/32 >= 3.
// MODE 0: raw split-K partial write (OT).  MODE 1: fused bias+relu -> bf16.
// MODE 2: fused bias -> f32.  (MODE 1/2 expect KC == 1.)
template <typename OT, int MODE>
__global__ __launch_bounds__(512, 2) void gemm8_kernel(const bf16_t* __restrict__ A,
                                                       const bf16_t* __restrict__ Bt,
                                                       OT* __restrict__ outp,
                                                       const float* __restrict__ bias,
                                                       int K, int kLen, int KC,
                                                       int GN, int ldc) {
  __shared__ __align__(16) bf16_t lds[4 * 2 * 2 * 128 * 32];  // 128 KiB
  const int t = threadIdx.x;
  const int lane = t & 63;
  const int w = t >> 6;         // 0..7
  const int wm = w >> 2;        // 0..1  (A-half / M region)
  const int wn = w & 3;         // 0..3  (64-col strip)
  const int bid = blockIdx.x;
  const int zc = bid % KC;      // K-chunk == XCD under round-robin dispatch
  const int inner = bid / KC;
  const int row0 = (inner / GN) * 256;
  const int col0 = (inner % GN) * 256;
  const int kOff = zc * kLen;
  const int G = kLen >> 5;      // 32-deep K-tiles (>= 3)

  const int lr = lane & 15;
  const int kb = (lane >> 4) * 16;
  int aoff[8], boff[4];
#pragma unroll
  for (int m = 0; m < 8; ++m) {
    int r = m * 16 + lr;
    aoff[m] = (r * 64 + kb) ^ (((r >> 3) & 1) << 5);
  }
#pragma unroll
  for (int n = 0; n < 4; ++n) {
    int r = (wn & 1) * 64 + n * 16 + lr;
    boff[n] = (r * 64 + kb) ^ (((r >> 3) & 1) << 5);
  }

  const int s_row = t >> 2;
  const int s_k8 = (t & 3) ^ (((s_row >> 3) & 1) << 1);
  const bf16_t* pAs = A + (size_t)(row0 + s_row) * K + kOff + s_k8 * 8;
  const bf16_t* pBs = Bt + (size_t)(col0 + s_row) * K + kOff + s_k8 * 8;
  const size_t halfStride = (size_t)128 * K;
  char* ldsBase = (char*)&lds[0];
  const int wOff = w << 10;

  auto stage = [&](int buf, int hp, int kt) {
    const bf16_t* src = ((hp < 2) ? pAs : pBs) + (size_t)(hp & 1) * halfStride + kt * 32;
    char* dst = ldsBase + buf * 32768 + (hp >> 1) * 16384 + (hp & 1) * 8192 + wOff;
    gload16(src, dst);
  };

  f32x4 acc[8][4] = {};

  // prologue: kt0->buf0, kt1->buf1, kt2->buf2; wait kt0 (vmcnt 8)
#pragma unroll
  for (int hp = 0; hp < 4; ++hp) stage(0, hp, 0);
#pragma unroll
  for (int hp = 0; hp < 4; ++hp) stage(1, hp, 1);
#pragma unroll
  for (int hp = 0; hp < 4; ++hp) stage(2, hp, 2);
  asm volatile("s_waitcnt vmcnt(8)" ::: "memory");
  __builtin_amdgcn_s_barrier();
  __builtin_amdgcn_sched_barrier(0);

  for (int g = 0; g < G; ++g) {
    const int cb = g & 3;
    const int sb = (g + 3) & 3;
    const bool doStage = (g + 3) < G;
    if (doStage) {
#pragma unroll
      for (int hp = 0; hp < 4; ++hp) stage(sb, hp, g + 3);
    }
    char* lA = ldsBase + cb * 32768 + wm * 8192;
    char* lB = ldsBase + cb * 32768 + 16384 + (wn >> 1) * 8192;
    bf16x8 af[8], bfv[4];
#pragma unroll
    for (int i = 0; i < 8; ++i) af[i] = *(const bf16x8*)(lA + aoff[i]);
#pragma unroll
    for (int j2 = 0; j2 < 4; ++j2) bfv[j2] = *(const bf16x8*)(lB + boff[j2]);
    asm volatile("s_waitcnt lgkmcnt(0)" ::: "memory");   // own frag reads landed
    if (doStage)          asm volatile("s_waitcnt vmcnt(8)" ::: "memory");  // kt g+1 landed
    else if (g == G - 3)  asm volatile("s_waitcnt vmcnt(4)" ::: "memory");
    else                  asm volatile("s_waitcnt vmcnt(0)" ::: "memory");
    __builtin_amdgcn_sched_barrier(0);
    __builtin_amdgcn_s_barrier();   // all waves: cb reads done + kt g+1 staged
    __builtin_amdgcn_sched_barrier(0);
    __builtin_amdgcn_s_setprio(1);
#pragma unroll
    for (int i = 0; i < 8; ++i)
#pragma unroll
      for (int j2 = 0; j2 < 4; ++j2)
        acc[i][j2] = __builtin_amdgcn_mfma_f32_16x16x32_bf16(af[i], bfv[j2], acc[i][j2], 0, 0, 0);
    __builtin_amdgcn_s_setprio(0);
    __builtin_amdgcn_sched_barrier(0);
  }

  // epilogue. C/D: col=lane&15, row=(lane>>4)*4+reg
  const int crow = (lane >> 4) * 4;
  if (MODE == 0) {
    OT* out = outp + (size_t)zc * MPAD * ldc;
#pragma unroll
    for (int n = 0; n < 4; ++n) {
      const int col = col0 + wn * 64 + n * 16 + lr;
#pragma unroll
      for (int m = 0; m < 8; ++m) {
        const int rowb = row0 + wm * 128 + m * 16 + crow;
#pragma unroll
        for (int j2 = 0; j2 < 4; ++j2)
          out[(size_t)(rowb + j2) * ldc + col] = (OT)acc[m][n][j2];
      }
    }
  } else {
#pragma unroll
    for (int n = 0; n < 4; ++n) {
      const int col = col0 + wn * 64 + n * 16 + lr;
      const float bv = bias[col];
#pragma unroll
      for (int m = 0; m < 8; ++m) {
        const int rowb = row0 + wm * 128 + m * 16 + crow;
#pragma unroll
        for (int j2 = 0; j2 < 4; ++j2) {
          float v = acc[m][n][j2] + bv;
          if (MODE == 1) v = fmaxf(v, 0.0f);
          outp[(size_t)(rowb + j2) * ldc + col] = (OT)v;
        }
      }
    }
  }
}

// ---------------- bf16 split-K reduce: out = relu(sum + bias) -> bf16 (8/thread) ----------------
__global__ __launch_bounds__(256) void reduceH_kernel(const bf16_t* __restrict__ partial,
                                                      const float* __restrict__ bias,
                                                      bf16_t* __restrict__ out,
                                                      int KC) {
  const size_t idx8 = ((size_t)blockIdx.x * 256 + threadIdx.x) * 8;  // over MPAD*REP_
  const size_t stride = (size_t)MPAD * REP_;
  float s[8] = {};
  for (int c = 0; c < KC; ++c) {
    const bf16x8 v = *(const bf16x8*)(partial + c * stride + idx8);
#pragma unroll
    for (int j = 0; j < 8; ++j) s[j] += (float)v[j];
  }
  const int col = (int)(idx8 & (size_t)(REP_ - 1));
  const f32x4 b0 = *(const f32x4*)(bias + col);
  const f32x4 b1 = *(const f32x4*)(bias + col + 4);
  bf16x8 o;
#pragma unroll
  for (int j = 0; j < 4; ++j) o[j] = (bf16_t)fmaxf(s[j] + b0[j], 0.0f);
#pragma unroll
  for (int j = 0; j < 4; ++j) o[4 + j] = (bf16_t)fmaxf(s[4 + j] + b1[j], 0.0f);
  *(bf16x8*)(out + idx8) = o;
}

// ---------------- row softmax stats: one wave per row ----------------
__global__ __launch_bounds__(256) void rowsm_kernel(const float* __restrict__ ho,
                                                    float* __restrict__ mxv,
                                                    float* __restrict__ invv) {
  const int row = blockIdx.x * 4 + (threadIdx.x >> 6);
  const int lane = threadIdx.x & 63;
  if (row >= M_) return;
  const float* r = ho + (size_t)row * HOUT;
  float v1 = (lane < NCLS) ? r[lane] : -3.0e38f;
  float v2 = (lane + 64 < NCLS) ? r[lane + 64] : -3.0e38f;
  float mx = fmaxf(v1, v2);
#pragma unroll
  for (int off = 32; off; off >>= 1) mx = fmaxf(mx, __shfl_xor(mx, off));
  float s = ((lane < NCLS) ? expf(v1 - mx) : 0.0f) + ((lane + 64 < NCLS) ? expf(v2 - mx) : 0.0f);
#pragma unroll
  for (int off = 32; off; off >>= 1) s += __shfl_xor(s, off);
  if (lane == 0) { mxv[row] = mx; invv[row] = 1.0f / s; }
}

// ---------------- decode + NMS prep: one thread per (roi, class) ----------------
__global__ __launch_bounds__(256) void decode_kernel(const float* __restrict__ ho,
                                                     const float* __restrict__ mxv,
                                                     const float* __restrict__ invv,
                                                     const float* __restrict__ props,
                                                     float* __restrict__ boxes,
                                                     float* __restrict__ scores,
                                                     float* __restrict__ swork,
                                                     float* __restrict__ boff,
                                                     float* __restrict__ area) {
  const int idx = blockIdx.x * 256 + threadIdx.x;
  if (idx >= M_ * 90) return;
  const int n = idx / 90;
  const int k = idx - n * 90 + 1;
  const float* row = ho + (size_t)n * HOUT;
  const float sc = expf(row[k] - mxv[n]) * invv[n];
  const float* p = props + n * 4;
  const float px1 = p[0], py1 = p[1], px2 = p[2], py2 = p[3];
  const float pw = px2 - px1, ph = py2 - py1;
  const float pcx = px1 + 0.5f * pw, pcy = py1 + 0.5f * ph;
  const float* d = row + NCLS + 4 * k;
  const float dx = d[0] * 0.1f;
  const float dy = d[1] * 0.1f;
  const float dw = fminf(d[2] * 0.2f, BBOX_CLIPF);
  const float dh = fminf(d[3] * 0.2f, BBOX_CLIPF);
  const float cx = dx * pw + pcx, cy = dy * ph + pcy;
  const float w = pw * expf(dw), h = ph * expf(dh);
  const float bx1 = fminf(fmaxf(cx - 0.5f * w, 0.0f), IMGF);
  const float by1 = fminf(fmaxf(cy - 0.5f * h, 0.0f), IMGF);
  const float bx2 = fminf(fmaxf(cx + 0.5f * w, 0.0f), IMGF);
  const float by2 = fminf(fmaxf(cy + 0.5f * h, 0.0f), IMGF);
  const int j = idx;
  boxes[4 * j + 0] = bx1; boxes[4 * j + 1] = by1;
  boxes[4 * j + 2] = bx2; boxes[4 * j + 3] = by2;
  scores[j] = sc;
  const float wv = bx2 - bx1, hv = by2 - by1;
  swork[j] = ((sc > 0.05f) && (wv >= 1.0f) && (hv >= 1.0f)) ? sc : NEGV;
  const float off = (float)k * (IMGF + 2.0f);
  const float ox1 = bx1 + off, oy1 = by1 + off, ox2 = bx2 + off, oy2 = by2 + off;
  boff[4 * j + 0] = ox1; boff[4 * j + 1] = oy1;
  boff[4 * j + 2] = ox2; boff[4 * j + 3] = oy2;
  area[j] = (ox2 - ox1) * (oy2 - oy1);
}

// ---------------- NMS: replicates jax.lax.scan semantics exactly ----------------
__global__ __launch_bounds__(1024) void nms_kernel(const float* __restrict__ boxes,
                                                   const float* __restrict__ scores,
                                                   float* __restrict__ swork,
                                                   const float* __restrict__ boff,
                                                   const float* __restrict__ area,
                                                   float* __restrict__ dout) {
  const int b = blockIdx.x;
  const int t = threadIdx.x;
  const float* Bx = boxes + (size_t)b * NMSM * 4;
  const float* Sc = scores + (size_t)b * NMSM;
  float* Sw = swork + (size_t)b * NMSM;
  const float* Bo = boff + (size_t)b * NMSM * 4;
  const float* Ar = area + (size_t)b * NMSM;
  float* dets = dout + b * (DET_ * 5);
  float* labels = dout + B_ * DET_ * 5 + b * DET_;
  __shared__ float s_val[1024];
  __shared__ int s_idx[1024];
  __shared__ float s_box[4];
  __shared__ float s_area;
  __shared__ int s_ok;
  for (int it = 0; it < DET_; ++it) {
    float bv = -3.0e38f;
    int bi = 0;
    for (int j = t; j < NMSM; j += 1024) {
      float v = Sw[j];
      if (v > bv) { bv = v; bi = j; }
    }
    s_val[t] = bv;
    s_idx[t] = bi;
    __syncthreads();
    for (int off = 512; off > 0; off >>= 1) {
      if (t < off) {
        float v2 = s_val[t + off]; int i2 = s_idx[t + off];
        if (v2 > s_val[t] || (v2 == s_val[t] && i2 < s_idx[t])) { s_val[t] = v2; s_idx[t] = i2; }
      }
      __syncthreads();
    }
    if (t == 0) {
      int i = s_idx[0];
      int ok = (s_val[0] > NEGV * 0.5f) ? 1 : 0;
      s_ok = ok;
      if (ok) {
        dets[it * 5 + 0] = Bx[i * 4 + 0];
        dets[it * 5 + 1] = Bx[i * 4 + 1];
        dets[it * 5 + 2] = Bx[i * 4 + 2];
        dets[it * 5 + 3] = Bx[i * 4 + 3];
        dets[it * 5 + 4] = Sc[i];
        labels[it] = (float)(i % 90 + 1);
        s_box[0] = Bo[i * 4 + 0]; s_box[1] = Bo[i * 4 + 1];
        s_box[2] = Bo[i * 4 + 2]; s_box[3] = Bo[i * 4 + 3];
        s_area = Ar[i];
        Sw[i] = NEGV;
      }
    }
    __syncthreads();
    if (!s_ok) {
      for (int tt = it + t; tt < DET_; tt += 1024) {
        dets[tt * 5 + 0] = 0.0f; dets[tt * 5 + 1] = 0.0f; dets[tt * 5 + 2] = 0.0f;
        dets[tt * 5 + 3] = 0.0f; dets[tt * 5 + 4] = 0.0f;
        labels[tt] = -1.0f;
      }
      return;
    }
    const float bx1 = s_box[0], by1 = s_box[1], bx2 = s_box[2], by2 = s_box[3], ai = s_area;
    for (int j = t; j < NMSM; j += 1024) {
      float v = Sw[j];
      if (v <= NEGV * 0.5f) continue;
      float ix1 = fmaxf(bx1, Bo[j * 4 + 0]);
      float iy1 = fmaxf(by1, Bo[j * 4 + 1]);
      float ix2 = fminf(bx2, Bo[j * 4 + 2]);
      float iy2 = fminf(by2, Bo[j * 4 + 3]);
      float inter = fmaxf(ix2 - ix1, 0.0f) * fmaxf(iy2 - iy1, 0.0f);
      float iou = inter / (ai + Ar[j] - inter + 1e-9f);
      if (iou > 0.5f) Sw[j] = NEGV;
    }
    __syncthreads();
  }
}

// ---------------- launch ----------------
extern "C" void kernel_launch(void* const* d_in, const int* in_sizes, int n_in,
                              void* d_out, int out_size, void* d_ws, size_t ws_size,
                              hipStream_t stream) {
  const float* features  = (const float*)d_in[0];
  const float* proposals = (const float*)d_in[1];
  const float* w1   = (const float*)d_in[2];
  const float* b1   = (const float*)d_in[3];
  const float* w2   = (const float*)d_in[4];
  const float* b2   = (const float*)d_in[5];
  const float* wcls = (const float*)d_in[6];
  const float* bcls = (const float*)d_in[7];
  const float* wbb  = (const float*)d_in[8];
  const float* bbb  = (const float*)d_in[9];
  (void)in_sizes; (void)n_in; (void)out_size;

  char* p = (char*)d_ws;
  auto alloc = [&](size_t bytes) {
    char* r = p;
    p += (bytes + 255) & ~(size_t)255;
    return r;
  };
  bf16_t* A      = (bf16_t*)alloc((size_t)MPAD * DIN * 2);
  bf16_t* w1t    = (bf16_t*)alloc((size_t)REP_ * DIN * 2);
  bf16_t* w2t    = (bf16_t*)alloc((size_t)REP_ * REP_ * 2);
  bf16_t* wht    = (bf16_t*)alloc((size_t)HOUT * REP_ * 2);
  float*  biash  = (float*)alloc((size_t)HOUT * 4);
  bf16_t* h1     = (bf16_t*)alloc((size_t)MPAD * REP_ * 2);
  bf16_t* h2     = (bf16_t*)alloc((size_t)MPAD * REP_ * 2);
  float*  ho     = (float*)alloc((size_t)MPAD * HOUT * 4);
  float*  mxv    = (float*)alloc((size_t)M_ * 4);
  float*  invv   = (float*)alloc((size_t)M_ * 4);
  float*  boxes  = (float*)alloc((size_t)B_ * NMSM * 4 * 4);
  float*  scoresb= (float*)alloc((size_t)B_ * NMSM * 4);
  float*  sworkb = (float*)alloc((size_t)B_ * NMSM * 4);
  float*  boffb  = (float*)alloc((size_t)B_ * NMSM * 4 * 4);
  float*  areab  = (float*)alloc((size_t)B_ * NMSM * 4);

  size_t used = (size_t)(p - (char*)d_ws);
  size_t avail = (ws_size > used) ? (ws_size - used) : 0;
  bf16_t* partialH = (bf16_t*)p;   // bf16 partials (FC1 only)
  const size_t chunkH = (size_t)MPAD * REP_ * 2;   // 4 MB
  int KC1 = 8;   // kLen = 1568, G = 49
  while (KC1 > 1 && (size_t)KC1 * chunkH > avail) KC1 >>= 1;

  // prep first: w1t/w2t/wht writebacks drain during roi's ~26us
  prep_kernel<<<NW1B + NW2B + NHWB + 1, 256, 0, stream>>>(w1, w2, wcls, wbb, bcls, bbb,
                                                          w1t, w2t, wht, biash);
  roi_kernel<<<dim3(C_ / CC_, (MPAD + RC_ - 1) / RC_), 256, 0, stream>>>(features, proposals, A);

  // FC1: [2048 x 12544] @ [12544 x 1024] -> h1 (relu, bf16). split-K=8, bf16 partials.
  gemm8_kernel<bf16_t, 0><<<32 * KC1, 512, 0, stream>>>(A, w1t, partialH, nullptr,
                                                        DIN, DIN / KC1, KC1, 4, REP_);
  reduceH_kernel<<<(MPAD * REP_ / 8) / 256, 256, 0, stream>>>(partialH, b1, h1, KC1);
  // FC2: [2048 x 1024] @ [1024 x 1024] -> h2 (relu, bf16). KC=1, G=32, fused epilogue.
  gemm8_kernel<bf16_t, 1><<<32, 512, 0, stream>>>(h1, w2t, h2, b2, REP_, REP_, 1, 4, REP_);
  // FC3 (heads): [2048 x 1024] @ [1024 x 512] -> ho (f32). KC=1, G=32, fused epilogue.
  gemm8_kernel<float, 2><<<16, 512, 0, stream>>>(h2, wht, ho, biash, REP_, REP_, 1, 2, HOUT);

  rowsm_kernel<<<(M_ + 3) / 4, 256, 0, stream>>>(ho, mxv, invv);
  decode_kernel<<<(M_ * 90 + 255) / 256, 256, 0, stream>>>(ho, mxv, invv, proposals,
                                                           boxes, scoresb, sworkb, boffb, areab);
  nms_kernel<<<B_, 1024, 0, stream>>>(boxes, scoresb, sworkb, boffb, areab, (float*)d_out);
}

// Round 13
// 195.690 us; speedup vs baseline: 1.0812x; 1.0812x over previous
//
#include <hip/hip_runtime.h>
#include <stdint.h>

// ---------------- problem constants (hard-coded from reference) ----------------
#define B_    2
#define N_    1000
#define C_    256
#define H_    50
#define W_    50
#define P_    7
#define NCLS  91
#define REP_  1024
#define DIN   (C_ * P_ * P_)   // 12544
#define M_    (B_ * N_)        // 2000
#define MPAD  2048
#define HOUT  512              // padded head cols (91 cls + 364 bbox = 455 real)
#define DET_  100
#define NMSM  (N_ * 90)        // 90000 candidates per batch
#define NEGV  (-1000000000.0f)
#define SCALE_ 0.0625f
#define IMGF  800.0f
#define BBOX_CLIPF 4.135166556742356f  // log(1000/16)

#define RC_   25               // rois per roi-chunk (1000 % 25 == 0: no batch mixing)
#define CC_   4                // channels per channel-chunk

typedef __bf16 bf16_t;
typedef __attribute__((ext_vector_type(8))) __bf16 bf16x8;
typedef __attribute__((ext_vector_type(4))) __bf16 bf16x4;
typedef __attribute__((ext_vector_type(4))) float f32x4;

// async global->LDS, 16B per lane. LDS dest must be wave-uniform base (+lane*16 by HW).
__device__ __forceinline__ void gload16(const void* g, void* l) {
  auto gp = (const __attribute__((address_space(1))) uint32_t*)(uintptr_t)g;
  auto lp = (__attribute__((address_space(3))) uint32_t*)(uint32_t)(uintptr_t)l;
  __builtin_amdgcn_global_load_lds(gp, lp, 16, 0, 0);
}

// ---------------- ROI align: LDS-staged feature planes, gathers from LDS ----------------
__global__ __launch_bounds__(256) void roi_kernel(const float* __restrict__ features,
                                                  const float* __restrict__ proposals,
                                                  bf16_t* __restrict__ A) {
  const int cc0 = blockIdx.x * CC_;       // channel base (0..252)
  const int roiBase = blockIdx.y * RC_;   // roi base
  const int t = threadIdx.x;
  if (roiBase >= M_) {
    for (int idx = t; idx < RC_ * 49; idx += 256) {
      const int r = idx / 49, pp = idx - r * 49;
      const int n = roiBase + r;
      if (n < MPAD) {
        bf16_t* arow = A + (size_t)n * DIN + cc0 * 49 + pp;
#pragma unroll
        for (int c = 0; c < CC_; ++c) arow[c * 49] = (bf16_t)0.0f;
      }
    }
    return;
  }
  __shared__ __align__(16) float s_pl[CC_ * 2500];   // 40000 B
  __shared__ float s_ly[RC_ * 49];
  __shared__ float s_lx[RC_ * 49];
  __shared__ unsigned short s_off[RC_ * 49];
  const int b = (roiBase >= N_) ? 1 : 0;
  const f32x4* src = (const f32x4*)(features + (size_t)(b * C_ + cc0) * (H_ * W_));
  f32x4* dst = (f32x4*)s_pl;
  for (int i = t; i < CC_ * 2500 / 4; i += 256) dst[i] = src[i];
  for (int idx = t; idx < RC_ * 49; idx += 256) {
    const int r = idx / 49, pp = idx - r * 49;
    const int py = pp / 7, px = pp - py * 7;
    const float* p = proposals + (roiBase + r) * 4;
    float y1 = p[1] * SCALE_, y2 = p[3] * SCALE_;
    float bh = (y2 - y1) * (1.0f / 7.0f);
    float y = y1 + ((float)py + 0.5f) * bh - 0.5f;
    y = fminf(fmaxf(y, 0.0f), 49.0f);
    int y0 = (int)floorf(y);
    int dy = (y0 < 49) ? 1 : 0;
    float ly = y - (float)y0;
    float x1 = p[0] * SCALE_, x2 = p[2] * SCALE_;
    float bw = (x2 - x1) * (1.0f / 7.0f);
    float x = x1 + ((float)px + 0.5f) * bw - 0.5f;
    x = fminf(fmaxf(x, 0.0f), 49.0f);
    int x0 = (int)floorf(x);
    int dx = (x0 < 49) ? 1 : 0;
    float lx = x - (float)x0;
    s_off[idx] = (unsigned short)((y0 * W_ + x0) | (dx << 12) | (dy << 13));
    s_ly[idx] = ly;
    s_lx[idx] = lx;
  }
  __syncthreads();
  for (int idx = t; idx < RC_ * 49; idx += 256) {
    const int r = idx / 49, pp = idx - r * 49;
    const unsigned off = s_off[idx];
    const float ly = s_ly[idx], lx = s_lx[idx];
    const float hy = 1.0f - ly, hx = 1.0f - lx;
    const int o00 = off & 0xFFF;
    const int dx = (off >> 12) & 1;
    const int o10 = o00 + W_ * ((off >> 13) & 1);
    const float w00 = hy * hx, w01 = hy * lx, w10 = ly * hx, w11 = ly * lx;
    bf16_t* arow = A + (size_t)(roiBase + r) * DIN + cc0 * 49 + pp;
#pragma unroll
    for (int c = 0; c < CC_; ++c) {
      const float* pl = s_pl + c * 2500;
      float v = pl[o00] * w00 + pl[o00 + dx] * w01 + pl[o10] * w10 + pl[o10 + dx] * w11;
      arow[c * 49] = (bf16_t)v;
    }
  }
}

// ---------------- transpose+convert: in f32 [K][N] -> out bf16 [N][K] ----------------
__global__ __launch_bounds__(256) void transpose_kernel(const float* __restrict__ in,
                                                        bf16_t* __restrict__ out,
                                                        int K, int N) {
  __shared__ float tile[32][33];
  const int k0 = blockIdx.x * 32;
  const int n0 = blockIdx.y * 32;
  const int tx = threadIdx.x & 31;
  const int ty = threadIdx.x >> 5;
#pragma unroll
  for (int j = 0; j < 4; ++j) {
    int ky = ty + j * 8;
    tile[ky][tx] = in[(size_t)(k0 + ky) * N + n0 + tx];
  }
  __syncthreads();
  const int qx = threadIdx.x & 7;
  const int ny = threadIdx.x >> 3;
  bf16x4 o;
#pragma unroll
  for (int i = 0; i < 4; ++i) o[i] = (bf16_t)tile[4 * qx + i][ny];
  *(bf16x4*)(&out[(size_t)(n0 + ny) * K + k0 + 4 * qx]) = o;
}

// ---------------- build concat head weight (B^T) and bias ----------------
__global__ __launch_bounds__(256) void headw_kernel(const float* __restrict__ wcls,
                                                    const float* __restrict__ wbb,
                                                    bf16_t* __restrict__ wht) {
  int idx = blockIdx.x * 256 + threadIdx.x;
  int j = idx >> 10;
  int k = idx & 1023;
  float v = 0.0f;
  if (j < NCLS) v = wcls[(size_t)k * NCLS + j];
  else if (j < 455) v = wbb[(size_t)k * 364 + (j - NCLS)];
  wht[idx] = (bf16_t)v;
}

__global__ void headb_kernel(const float* __restrict__ bcls,
                             const float* __restrict__ bbb,
                             float* __restrict__ biash) {
  int j = threadIdx.x;
  float v = 0.0f;
  if (j < NCLS) v = bcls[j];
  else if (j < 455) v = bbb[j - NCLS];
  biash[j] = v;
}

// ---------------- FC1: 256x256-tile deep-pipelined MFMA GEMM (8-wave, split-K) ----------------
// 4 LDS buffers (128 KiB), depth-3 prefetch (stage kt g+3 FIRST, steady vmcnt(8)),
// one-shot frag reads, single barrier/K-tile (before MFMA), st_16x32 swizzle both-sides,
// zc = bid % KC pins each K-chunk to one XCD. Partials written as bf16.  [R9-proven: 57us]
__global__ __launch_bounds__(512, 2) void gemm8_kernel(const bf16_t* __restrict__ A,
                                                       const bf16_t* __restrict__ Bt,
                                                       bf16_t* __restrict__ partial,
                                                       int K, int kLen, int KC) {
  __shared__ __align__(16) bf16_t lds[4 * 2 * 2 * 128 * 32];  // 128 KiB
  const int t = threadIdx.x;
  const int lane = t & 63;
  const int w = t >> 6;         // 0..7
  const int wm = w >> 2;        // 0..1  (A-half / M region)
  const int wn = w & 3;         // 0..3  (64-col strip)
  const int bid = blockIdx.x;
  const int zc = bid % KC;      // K-chunk == XCD under round-robin dispatch
  const int inner = bid / KC;   // 0..31
  const int row0 = (inner >> 2) * 256;
  const int col0 = (inner & 3) * 256;
  const int kOff = zc * kLen;
  const int G = kLen >> 5;      // 32-deep K-tiles (>= 3)

  const int lr = lane & 15;
  const int kb = (lane >> 4) * 16;
  int aoff[8], boff[4];
#pragma unroll
  for (int m = 0; m < 8; ++m) {
    int r = m * 16 + lr;
    aoff[m] = (r * 64 + kb) ^ (((r >> 3) & 1) << 5);
  }
#pragma unroll
  for (int n = 0; n < 4; ++n) {
    int r = (wn & 1) * 64 + n * 16 + lr;
    boff[n] = (r * 64 + kb) ^ (((r >> 3) & 1) << 5);
  }

  const int s_row = t >> 2;
  const int s_k8 = (t & 3) ^ (((s_row >> 3) & 1) << 1);
  const bf16_t* pAs = A + (size_t)(row0 + s_row) * K + kOff + s_k8 * 8;
  const bf16_t* pBs = Bt + (size_t)(col0 + s_row) * K + kOff + s_k8 * 8;
  const size_t halfStride = (size_t)128 * K;
  char* ldsBase = (char*)&lds[0];
  const int wOff = w << 10;

  auto stage = [&](int buf, int hp, int kt) {
    const bf16_t* src = ((hp < 2) ? pAs : pBs) + (size_t)(hp & 1) * halfStride + kt * 32;
    char* dst = ldsBase + buf * 32768 + (hp >> 1) * 16384 + (hp & 1) * 8192 + wOff;
    gload16(src, dst);
  };

  f32x4 acc[8][4] = {};

  // prologue: kt0->buf0, kt1->buf1, kt2->buf2; wait kt0 (vmcnt 8)
#pragma unroll
  for (int hp = 0; hp < 4; ++hp) stage(0, hp, 0);
#pragma unroll
  for (int hp = 0; hp < 4; ++hp) stage(1, hp, 1);
#pragma unroll
  for (int hp = 0; hp < 4; ++hp) stage(2, hp, 2);
  asm volatile("s_waitcnt vmcnt(8)" ::: "memory");
  __builtin_amdgcn_s_barrier();
  __builtin_amdgcn_sched_barrier(0);

  for (int g = 0; g < G; ++g) {
    const int cb = g & 3;
    const int sb = (g + 3) & 3;
    const bool doStage = (g + 3) < G;
    if (doStage) {
#pragma unroll
      for (int hp = 0; hp < 4; ++hp) stage(sb, hp, g + 3);
    }
    char* lA = ldsBase + cb * 32768 + wm * 8192;
    char* lB = ldsBase + cb * 32768 + 16384 + (wn >> 1) * 8192;
    bf16x8 af[8], bfv[4];
#pragma unroll
    for (int i = 0; i < 8; ++i) af[i] = *(const bf16x8*)(lA + aoff[i]);
#pragma unroll
    for (int j2 = 0; j2 < 4; ++j2) bfv[j2] = *(const bf16x8*)(lB + boff[j2]);
    asm volatile("s_waitcnt lgkmcnt(0)" ::: "memory");   // own frag reads landed
    if (doStage)          asm volatile("s_waitcnt vmcnt(8)" ::: "memory");  // kt g+1 landed
    else if (g == G - 3)  asm volatile("s_waitcnt vmcnt(4)" ::: "memory");
    else                  asm volatile("s_waitcnt vmcnt(0)" ::: "memory");
    __builtin_amdgcn_sched_barrier(0);
    __builtin_amdgcn_s_barrier();   // all waves: cb reads done + kt g+1 staged
    __builtin_amdgcn_sched_barrier(0);
    __builtin_amdgcn_s_setprio(1);
#pragma unroll
    for (int i = 0; i < 8; ++i)
#pragma unroll
      for (int j2 = 0; j2 < 4; ++j2)
        acc[i][j2] = __builtin_amdgcn_mfma_f32_16x16x32_bf16(af[i], bfv[j2], acc[i][j2], 0, 0, 0);
    __builtin_amdgcn_s_setprio(0);
    __builtin_amdgcn_sched_barrier(0);
  }

  // epilogue: bf16 partial write. C/D: col=lane&15, row=(lane>>4)*4+reg
  bf16_t* out = partial + (size_t)zc * MPAD * REP_;
  const int crow = (lane >> 4) * 4;
#pragma unroll
  for (int n = 0; n < 4; ++n) {
    const int col = col0 + wn * 64 + n * 16 + lr;
#pragma unroll
    for (int m = 0; m < 8; ++m) {
      const int rowb = row0 + wm * 128 + m * 16 + crow;
#pragma unroll
      for (int j2 = 0; j2 < 4; ++j2)
        out[(size_t)(rowb + j2) * REP_ + col] = (bf16_t)acc[m][n][j2];
    }
  }
}

// ---------------- FC2/FC3: 128x128-tile 2-phase GEMM, split-K (R9 config) ----------------
__global__ __launch_bounds__(256) void gemm_kernel(const bf16_t* __restrict__ A,
                                                   const bf16_t* __restrict__ Bt,
                                                   float* __restrict__ partial,
                                                   int K, int ldc, int kLen) {
  __shared__ __align__(16) bf16_t As[128 * 32];
  __shared__ __align__(16) bf16_t Bs[128 * 32];
  const int t = threadIdx.x;
  const int lane = t & 63;
  const int wid = t >> 6;
  const int row0 = blockIdx.x * 128;
  const int col0 = blockIdx.y * 128;
  const int kOff = blockIdx.z * kLen;

  f32x4 acc[4][4] = {};

  const int rA = t >> 2;
  const int sA = t & 3;
  const bf16_t* aSrc1 = A + (size_t)(row0 + rA) * K + sA * 8 + kOff;
  const bf16_t* aSrc2 = A + (size_t)(row0 + rA + 64) * K + sA * 8 + kOff;
  const bf16_t* bSrc1 = Bt + (size_t)(col0 + rA) * K + sA * 8 + kOff;
  const bf16_t* bSrc2 = Bt + (size_t)(col0 + rA + 64) * K + sA * 8 + kOff;
  char* AsB = (char*)&As[0];
  char* BsB = (char*)&Bs[0];
  const int ldsOff1 = (wid * 64) * 16;
  const int ldsOff2 = (wid * 64 + 256) * 16;

  const int wm = wid >> 1;
  const int wn = wid & 1;
  const int lr = lane & 15;
  const int lk16 = (lane >> 4) * 16;
  int aOff[4], bOff[4];
#pragma unroll
  for (int m = 0; m < 4; ++m) aOff[m] = (wm * 64 + m * 16 + lr) * 64 + lk16;
#pragma unroll
  for (int n = 0; n < 4; ++n) bOff[n] = (wn * 64 + n * 16 + lr) * 64 + lk16;

  for (int k0 = 0; k0 < kLen; k0 += 32) {
    gload16(aSrc1 + k0, AsB + ldsOff1);
    gload16(aSrc2 + k0, AsB + ldsOff2);
    gload16(bSrc1 + k0, BsB + ldsOff1);
    gload16(bSrc2 + k0, BsB + ldsOff2);
    __syncthreads();
    bf16x8 af[4], bfv[4];
#pragma unroll
    for (int m = 0; m < 4; ++m) af[m] = *(const bf16x8*)(AsB + aOff[m]);
#pragma unroll
    for (int n = 0; n < 4; ++n) bfv[n] = *(const bf16x8*)(BsB + bOff[n]);
#pragma unroll
    for (int m = 0; m < 4; ++m)
#pragma unroll
      for (int n = 0; n < 4; ++n)
        acc[m][n] = __builtin_amdgcn_mfma_f32_16x16x32_bf16(af[m], bfv[n], acc[m][n], 0, 0, 0);
    __syncthreads();
  }

  float* out = partial + (size_t)blockIdx.z * MPAD * ldc;
  const int crow = (lane >> 4) * 4;
  const int ccol = lane & 15;
#pragma unroll
  for (int n = 0; n < 4; ++n) {
    const int col = col0 + wn * 64 + n * 16 + ccol;
#pragma unroll
    for (int m = 0; m < 4; ++m) {
      const int rowb = row0 + wm * 64 + m * 16 + crow;
#pragma unroll
      for (int j = 0; j < 4; ++j) {
        out[(size_t)(rowb + j) * ldc + col] = acc[m][n][j];
      }
    }
  }
}

// ---------------- FC1 reduce: bf16 partials -> relu -> bf16 out (8 elems/thread) ----------------
__global__ __launch_bounds__(256) void reduceH_kernel(const bf16_t* __restrict__ partial,
                                                      const float* __restrict__ bias,
                                                      bf16_t* __restrict__ out,
                                                      int KC) {
  const size_t idx8 = ((size_t)blockIdx.x * 256 + threadIdx.x) * 8;  // over MPAD*REP_
  const size_t stride = (size_t)MPAD * REP_;
  float s[8] = {};
  for (int c = 0; c < KC; ++c) {
    const bf16x8 v = *(const bf16x8*)(partial + c * stride + idx8);
#pragma unroll
    for (int j = 0; j < 8; ++j) s[j] += (float)v[j];
  }
  const int col = (int)(idx8 & (size_t)(REP_ - 1));
  const f32x4 b0 = *(const f32x4*)(bias + col);
  const f32x4 b1 = *(const f32x4*)(bias + col + 4);
  bf16x8 o;
#pragma unroll
  for (int j = 0; j < 4; ++j) o[j] = (bf16_t)fmaxf(s[j] + b0[j], 0.0f);
#pragma unroll
  for (int j = 0; j < 4; ++j) o[4 + j] = (bf16_t)fmaxf(s[4 + j] + b1[j], 0.0f);
  *(bf16x8*)(out + idx8) = o;
}

// ---------------- split-K reduce (f32 partials) ----------------
__global__ __launch_bounds__(256) void reduce_kernel(const float* __restrict__ partial,
                                                     const float* __restrict__ bias,
                                                     void* __restrict__ out,
                                                     int ldc, int KC, int mode) {
  const size_t idx4 = ((size_t)blockIdx.x * 256 + threadIdx.x) * 4;
  f32x4 s = *(const f32x4*)(partial + idx4);
  const size_t stride = (size_t)MPAD * ldc;
  for (int c = 1; c < KC; ++c) s += *(const f32x4*)(partial + c * stride + idx4);
  const int col = (int)(idx4 & (size_t)(ldc - 1));
  const f32x4 bv = *(const f32x4*)(bias + col);
  s += bv;
  if (mode) {
    bf16x4 o;
#pragma unroll
    for (int j = 0; j < 4; ++j) o[j] = (bf16_t)fmaxf(s[j], 0.0f);
    *(bf16x4*)((bf16_t*)out + idx4) = o;
  } else {
    *(f32x4*)((float*)out + idx4) = s;
  }
}

// ---------------- row softmax stats: one wave per row ----------------
__global__ __launch_bounds__(256) void rowsm_kernel(const float* __restrict__ ho,
                                                    float* __restrict__ mxv,
                                                    float* __restrict__ invv) {
  const int row = blockIdx.x * 4 + (threadIdx.x >> 6);
  const int lane = threadIdx.x & 63;
  if (row >= M_) return;
  const float* r = ho + (size_t)row * HOUT;
  float v1 = (lane < NCLS) ? r[lane] : -3.0e38f;
  float v2 = (lane + 64 < NCLS) ? r[lane + 64] : -3.0e38f;
  float mx = fmaxf(v1, v2);
#pragma unroll
  for (int off = 32; off; off >>= 1) mx = fmaxf(mx, __shfl_xor(mx, off));
  float s = ((lane < NCLS) ? expf(v1 - mx) : 0.0f) + ((lane + 64 < NCLS) ? expf(v2 - mx) : 0.0f);
#pragma unroll
  for (int off = 32; off; off >>= 1) s += __shfl_xor(s, off);
  if (lane == 0) { mxv[row] = mx; invv[row] = 1.0f / s; }
}

// ---------------- decode + NMS prep: one thread per (roi, class) ----------------
__global__ __launch_bounds__(256) void decode_kernel(const float* __restrict__ ho,
                                                     const float* __restrict__ mxv,
                                                     const float* __restrict__ invv,
                                                     const float* __restrict__ props,
                                                     float* __restrict__ boxes,
                                                     float* __restrict__ scores,
                                                     float* __restrict__ swork,
                                                     float* __restrict__ boff,
                                                     float* __restrict__ area) {
  const int idx = blockIdx.x * 256 + threadIdx.x;
  if (idx >= M_ * 90) return;
  const int n = idx / 90;
  const int k = idx - n * 90 + 1;
  const float* row = ho + (size_t)n * HOUT;
  const float sc = expf(row[k] - mxv[n]) * invv[n];
  const float* p = props + n * 4;
  const float px1 = p[0], py1 = p[1], px2 = p[2], py2 = p[3];
  const float pw = px2 - px1, ph = py2 - py1;
  const float pcx = px1 + 0.5f * pw, pcy = py1 + 0.5f * ph;
  const float* d = row + NCLS + 4 * k;
  const float dx = d[0] * 0.1f;
  const float dy = d[1] * 0.1f;
  const float dw = fminf(d[2] * 0.2f, BBOX_CLIPF);
  const float dh = fminf(d[3] * 0.2f, BBOX_CLIPF);
  const float cx = dx * pw + pcx, cy = dy * ph + pcy;
  const float w = pw * expf(dw), h = ph * expf(dh);
  const float bx1 = fminf(fmaxf(cx - 0.5f * w, 0.0f), IMGF);
  const float by1 = fminf(fmaxf(cy - 0.5f * h, 0.0f), IMGF);
  const float bx2 = fminf(fmaxf(cx + 0.5f * w, 0.0f), IMGF);
  const float by2 = fminf(fmaxf(cy + 0.5f * h, 0.0f), IMGF);
  const int j = idx;
  boxes[4 * j + 0] = bx1; boxes[4 * j + 1] = by1;
  boxes[4 * j + 2] = bx2; boxes[4 * j + 3] = by2;
  scores[j] = sc;
  const float wv = bx2 - bx1, hv = by2 - by1;
  swork[j] = ((sc > 0.05f) && (wv >= 1.0f) && (hv >= 1.0f)) ? sc : NEGV;
  const float off = (float)k * (IMGF + 2.0f);
  const float ox1 = bx1 + off, oy1 = by1 + off, ox2 = bx2 + off, oy2 = by2 + off;
  boff[4 * j + 0] = ox1; boff[4 * j + 1] = oy1;
  boff[4 * j + 2] = ox2; boff[4 * j + 3] = oy2;
  area[j] = (ox2 - ox1) * (oy2 - oy1);
}

// ---------------- NMS: replicates jax.lax.scan semantics exactly ----------------
__global__ __launch_bounds__(1024) void nms_kernel(const float* __restrict__ boxes,
                                                   const float* __restrict__ scores,
                                                   float* __restrict__ swork,
                                                   const float* __restrict__ boff,
                                                   const float* __restrict__ area,
                                                   float* __restrict__ dout) {
  const int b = blockIdx.x;
  const int t = threadIdx.x;
  const float* Bx = boxes + (size_t)b * NMSM * 4;
  const float* Sc = scores + (size_t)b * NMSM;
  float* Sw = swork + (size_t)b * NMSM;
  const float* Bo = boff + (size_t)b * NMSM * 4;
  const float* Ar = area + (size_t)b * NMSM;
  float* dets = dout + b * (DET_ * 5);
  float* labels = dout + B_ * DET_ * 5 + b * DET_;
  __shared__ float s_val[1024];
  __shared__ int s_idx[1024];
  __shared__ float s_box[4];
  __shared__ float s_area;
  __shared__ int s_ok;
  for (int it = 0; it < DET_; ++it) {
    float bv = -3.0e38f;
    int bi = 0;
    for (int j = t; j < NMSM; j += 1024) {
      float v = Sw[j];
      if (v > bv) { bv = v; bi = j; }
    }
    s_val[t] = bv;
    s_idx[t] = bi;
    __syncthreads();
    for (int off = 512; off > 0; off >>= 1) {
      if (t < off) {
        float v2 = s_val[t + off]; int i2 = s_idx[t + off];
        if (v2 > s_val[t] || (v2 == s_val[t] && i2 < s_idx[t])) { s_val[t] = v2; s_idx[t] = i2; }
      }
      __syncthreads();
    }
    if (t == 0) {
      int i = s_idx[0];
      int ok = (s_val[0] > NEGV * 0.5f) ? 1 : 0;
      s_ok = ok;
      if (ok) {
        dets[it * 5 + 0] = Bx[i * 4 + 0];
        dets[it * 5 + 1] = Bx[i * 4 + 1];
        dets[it * 5 + 2] = Bx[i * 4 + 2];
        dets[it * 5 + 3] = Bx[i * 4 + 3];
        dets[it * 5 + 4] = Sc[i];
        labels[it] = (float)(i % 90 + 1);
        s_box[0] = Bo[i * 4 + 0]; s_box[1] = Bo[i * 4 + 1];
        s_box[2] = Bo[i * 4 + 2]; s_box[3] = Bo[i * 4 + 3];
        s_area = Ar[i];
        Sw[i] = NEGV;
      }
    }
    __syncthreads();
    if (!s_ok) {
      for (int tt = it + t; tt < DET_; tt += 1024) {
        dets[tt * 5 + 0] = 0.0f; dets[tt * 5 + 1] = 0.0f; dets[tt * 5 + 2] = 0.0f;
        dets[tt * 5 + 3] = 0.0f; dets[tt * 5 + 4] = 0.0f;
        labels[tt] = -1.0f;
      }
      return;
    }
    const float bx1 = s_box[0], by1 = s_box[1], bx2 = s_box[2], by2 = s_box[3], ai = s_area;
    for (int j = t; j < NMSM; j += 1024) {
      float v = Sw[j];
      if (v <= NEGV * 0.5f) continue;
      float ix1 = fmaxf(bx1, Bo[j * 4 + 0]);
      float iy1 = fmaxf(by1, Bo[j * 4 + 1]);
      float ix2 = fminf(bx2, Bo[j * 4 + 2]);
      float iy2 = fminf(by2, Bo[j * 4 + 3]);
      float inter = fmaxf(ix2 - ix1, 0.0f) * fmaxf(iy2 - iy1, 0.0f);
      float iou = inter / (ai + Ar[j] - inter + 1e-9f);
      if (iou > 0.5f) Sw[j] = NEGV;
    }
    __syncthreads();
  }
}

// ---------------- launch ----------------
extern "C" void kernel_launch(void* const* d_in, const int* in_sizes, int n_in,
                              void* d_out, int out_size, void* d_ws, size_t ws_size,
                              hipStream_t stream) {
  const float* features  = (const float*)d_in[0];
  const float* proposals = (const float*)d_in[1];
  const float* w1   = (const float*)d_in[2];
  const float* b1   = (const float*)d_in[3];
  const float* w2   = (const float*)d_in[4];
  const float* b2   = (const float*)d_in[5];
  const float* wcls = (const float*)d_in[6];
  const float* bcls = (const float*)d_in[7];
  const float* wbb  = (const float*)d_in[8];
  const float* bbb  = (const float*)d_in[9];
  (void)in_sizes; (void)n_in; (void)out_size;

  char* p = (char*)d_ws;
  auto alloc = [&](size_t bytes) {
    char* r = p;
    p += (bytes + 255) & ~(size_t)255;
    return r;
  };
  bf16_t* A      = (bf16_t*)alloc((size_t)MPAD * DIN * 2);
  bf16_t* w1t    = (bf16_t*)alloc((size_t)REP_ * DIN * 2);
  bf16_t* w2t    = (bf16_t*)alloc((size_t)REP_ * REP_ * 2);
  bf16_t* wht    = (bf16_t*)alloc((size_t)HOUT * REP_ * 2);
  float*  biash  = (float*)alloc((size_t)HOUT * 4);
  bf16_t* h1     = (bf16_t*)alloc((size_t)MPAD * REP_ * 2);
  bf16_t* h2     = (bf16_t*)alloc((size_t)MPAD * REP_ * 2);
  float*  ho     = (float*)alloc((size_t)MPAD * HOUT * 4);
  float*  mxv    = (float*)alloc((size_t)M_ * 4);
  float*  invv   = (float*)alloc((size_t)M_ * 4);
  float*  boxes  = (float*)alloc((size_t)B_ * NMSM * 4 * 4);
  float*  scoresb= (float*)alloc((size_t)B_ * NMSM * 4);
  float*  sworkb = (float*)alloc((size_t)B_ * NMSM * 4);
  float*  boffb  = (float*)alloc((size_t)B_ * NMSM * 4 * 4);
  float*  areab  = (float*)alloc((size_t)B_ * NMSM * 4);

  size_t used = (size_t)(p - (char*)d_ws);
  size_t avail = (ws_size > used) ? (ws_size - used) : 0;
  bf16_t* partialH = (bf16_t*)p;   // bf16 partials (FC1)
  float*  partialF = (float*)p;    // f32 partials (FC2/FC3, stream-ordered reuse)
  const size_t chunkH = (size_t)MPAD * REP_ * 2;   // 4 MB
  const size_t chunkF = (size_t)MPAD * REP_ * 4;   // 8 MB
  int KC1 = 8;
  while (KC1 > 1 && (size_t)KC1 * chunkH > avail) KC1 >>= 1;
  int KC2 = 4;
  while (KC2 > 1 && (size_t)KC2 * chunkF > avail) KC2 >>= 1;
  int KC3 = 4;

  // ONLY delta vs R9: weight-prep launched BEFORE roi (writebacks drain under roi)
  transpose_kernel<<<dim3(DIN / 32, REP_ / 32), 256, 0, stream>>>(w1, w1t, DIN, REP_);
  transpose_kernel<<<dim3(REP_ / 32, REP_ / 32), 256, 0, stream>>>(w2, w2t, REP_, REP_);
  headw_kernel<<<(HOUT * REP_) / 256, 256, 0, stream>>>(wcls, wbb, wht);
  headb_kernel<<<1, HOUT, 0, stream>>>(bcls, bbb, biash);
  roi_kernel<<<dim3(C_ / CC_, (MPAD + RC_ - 1) / RC_), 256, 0, stream>>>(features, proposals, A);

  // FC1: [2048 x 12544] @ [12544 x 1024] -> h1 (relu, bf16). 8-wave depth-3 pipeline.
  gemm8_kernel<<<32 * KC1, 512, 0, stream>>>(A, w1t, partialH, DIN, DIN / KC1, KC1);
  reduceH_kernel<<<(MPAD * REP_ / 8) / 256, 256, 0, stream>>>(partialH, b1, h1, KC1);
  // FC2: [2048 x 1024] @ [1024 x 1024] -> h2 (relu, bf16)
  gemm_kernel<<<dim3(MPAD / 128, REP_ / 128, KC2), 256, 0, stream>>>(h1, w2t, partialF, REP_, REP_, REP_ / KC2);
  reduce_kernel<<<(MPAD * REP_ / 4) / 256, 256, 0, stream>>>(partialF, b2, h2, REP_, KC2, 1);
  // FC3 (heads): [2048 x 1024] @ [1024 x 512] -> ho (f32)
  gemm_kernel<<<dim3(MPAD / 128, HOUT / 128, KC3), 256, 0, stream>>>(h2, wht, partialF, REP_, HOUT, REP_ / KC3);
  reduce_kernel<<<(MPAD * HOUT / 4) / 256, 256, 0, stream>>>(partialF, biash, ho, HOUT, KC3, 0);

  rowsm_kernel<<<(M_ + 3) / 4, 256, 0, stream>>>(ho, mxv, invv);
  decode_kernel<<<(M_ * 90 + 255) / 256, 256, 0, stream>>>(ho, mxv, invv, proposals,
                                                           boxes, scoresb, sworkb, boffb, areab);
  nms_kernel<<<B_, 1024, 0, stream>>>(boxes, scoresb, sworkb, boffb, areab, (float*)d_out);
}

// Round 14
// 183.121 us; speedup vs baseline: 1.1554x; 1.0686x over previous
//
#include <hip/hip_runtime.h>
#include <stdint.h>

// ---------------- problem constants (hard-coded from reference) ----------------
#define B_    2
#define N_    1000
#define C_    256
#define H_    50
#define W_    50
#define P_    7
#define NCLS  91
#define REP_  1024
#define DIN   (C_ * P_ * P_)   // 12544
#define M_    (B_ * N_)        // 2000
#define MPAD  2048
#define HOUT  512              // padded head cols (91 cls + 364 bbox = 455 real)
#define DET_  100
#define NMSM  (N_ * 90)        // 90000 candidates per batch
#define NEGV  (-1000000000.0f)
#define SCALE_ 0.0625f
#define IMGF  800.0f
#define BBOX_CLIPF 4.135166556742356f  // log(1000/16)

#define RC_   25               // rois per roi-chunk (1000 % 25 == 0: no batch mixing)
#define CC_   4                // channels per channel-chunk

typedef __bf16 bf16_t;
typedef __attribute__((ext_vector_type(8))) __bf16 bf16x8;
typedef __attribute__((ext_vector_type(4))) __bf16 bf16x4;
typedef __attribute__((ext_vector_type(4))) float f32x4;

// async global->LDS, 16B per lane. LDS dest must be wave-uniform base (+lane*16 by HW).
__device__ __forceinline__ void gload16(const void* g, void* l) {
  auto gp = (const __attribute__((address_space(1))) uint32_t*)(uintptr_t)g;
  auto lp = (__attribute__((address_space(3))) uint32_t*)(uint32_t)(uintptr_t)l;
  __builtin_amdgcn_global_load_lds(gp, lp, 16, 0, 0);
}

// ---------------- ROI align: LDS-staged feature planes, gathers from LDS ----------------
__global__ __launch_bounds__(256) void roi_kernel(const float* __restrict__ features,
                                                  const float* __restrict__ proposals,
                                                  bf16_t* __restrict__ A) {
  const int cc0 = blockIdx.x * CC_;       // channel base (0..252)
  const int roiBase = blockIdx.y * RC_;   // roi base
  const int t = threadIdx.x;
  if (roiBase >= M_) {
    for (int idx = t; idx < RC_ * 49; idx += 256) {
      const int r = idx / 49, pp = idx - r * 49;
      const int n = roiBase + r;
      if (n < MPAD) {
        bf16_t* arow = A + (size_t)n * DIN + cc0 * 49 + pp;
#pragma unroll
        for (int c = 0; c < CC_; ++c) arow[c * 49] = (bf16_t)0.0f;
      }
    }
    return;
  }
  __shared__ __align__(16) float s_pl[CC_ * 2500];   // 40000 B
  __shared__ float s_ly[RC_ * 49];
  __shared__ float s_lx[RC_ * 49];
  __shared__ unsigned short s_off[RC_ * 49];
  const int b = (roiBase >= N_) ? 1 : 0;
  const f32x4* src = (const f32x4*)(features + (size_t)(b * C_ + cc0) * (H_ * W_));
  f32x4* dst = (f32x4*)s_pl;
  for (int i = t; i < CC_ * 2500 / 4; i += 256) dst[i] = src[i];
  for (int idx = t; idx < RC_ * 49; idx += 256) {
    const int r = idx / 49, pp = idx - r * 49;
    const int py = pp / 7, px = pp - py * 7;
    const float* p = proposals + (roiBase + r) * 4;
    float y1 = p[1] * SCALE_, y2 = p[3] * SCALE_;
    float bh = (y2 - y1) * (1.0f / 7.0f);
    float y = y1 + ((float)py + 0.5f) * bh - 0.5f;
    y = fminf(fmaxf(y, 0.0f), 49.0f);
    int y0 = (int)floorf(y);
    int dy = (y0 < 49) ? 1 : 0;
    float ly = y - (float)y0;
    float x1 = p[0] * SCALE_, x2 = p[2] * SCALE_;
    float bw = (x2 - x1) * (1.0f / 7.0f);
    float x = x1 + ((float)px + 0.5f) * bw - 0.5f;
    x = fminf(fmaxf(x, 0.0f), 49.0f);
    int x0 = (int)floorf(x);
    int dx = (x0 < 49) ? 1 : 0;
    float lx = x - (float)x0;
    s_off[idx] = (unsigned short)((y0 * W_ + x0) | (dx << 12) | (dy << 13));
    s_ly[idx] = ly;
    s_lx[idx] = lx;
  }
  __syncthreads();
  for (int idx = t; idx < RC_ * 49; idx += 256) {
    const int r = idx / 49, pp = idx - r * 49;
    const unsigned off = s_off[idx];
    const float ly = s_ly[idx], lx = s_lx[idx];
    const float hy = 1.0f - ly, hx = 1.0f - lx;
    const int o00 = off & 0xFFF;
    const int dx = (off >> 12) & 1;
    const int o10 = o00 + W_ * ((off >> 13) & 1);
    const float w00 = hy * hx, w01 = hy * lx, w10 = ly * hx, w11 = ly * lx;
    bf16_t* arow = A + (size_t)(roiBase + r) * DIN + cc0 * 49 + pp;
#pragma unroll
    for (int c = 0; c < CC_; ++c) {
      const float* pl = s_pl + c * 2500;
      float v = pl[o00] * w00 + pl[o00 + dx] * w01 + pl[o10] * w10 + pl[o10 + dx] * w11;
      arow[c * 49] = (bf16_t)v;
    }
  }
}

// ---------------- transpose+convert: in f32 [K][N] -> out bf16 [N][K] ----------------
__global__ __launch_bounds__(256) void transpose_kernel(const float* __restrict__ in,
                                                        bf16_t* __restrict__ out,
                                                        int K, int N) {
  __shared__ float tile[32][33];
  const int k0 = blockIdx.x * 32;
  const int n0 = blockIdx.y * 32;
  const int tx = threadIdx.x & 31;
  const int ty = threadIdx.x >> 5;
#pragma unroll
  for (int j = 0; j < 4; ++j) {
    int ky = ty + j * 8;
    tile[ky][tx] = in[(size_t)(k0 + ky) * N + n0 + tx];
  }
  __syncthreads();
  const int qx = threadIdx.x & 7;
  const int ny = threadIdx.x >> 3;
  bf16x4 o;
#pragma unroll
  for (int i = 0; i < 4; ++i) o[i] = (bf16_t)tile[4 * qx + i][ny];
  *(bf16x4*)(&out[(size_t)(n0 + ny) * K + k0 + 4 * qx]) = o;
}

// ---------------- build concat head weight (B^T) and bias ----------------
__global__ __launch_bounds__(256) void headw_kernel(const float* __restrict__ wcls,
                                                    const float* __restrict__ wbb,
                                                    bf16_t* __restrict__ wht) {
  int idx = blockIdx.x * 256 + threadIdx.x;
  int j = idx >> 10;
  int k = idx & 1023;
  float v = 0.0f;
  if (j < NCLS) v = wcls[(size_t)k * NCLS + j];
  else if (j < 455) v = wbb[(size_t)k * 364 + (j - NCLS)];
  wht[idx] = (bf16_t)v;
}

__global__ void headb_kernel(const float* __restrict__ bcls,
                             const float* __restrict__ bbb,
                             float* __restrict__ biash) {
  int j = threadIdx.x;
  float v = 0.0f;
  if (j < NCLS) v = bcls[j];
  else if (j < 455) v = bbb[j - NCLS];
  biash[j] = v;
}

// ---------------- FC1: 256x256-tile deep-pipelined MFMA GEMM (8-wave, split-K) ----------------
// [R9-proven: 57us] 4 LDS buffers (128 KiB), depth-3 prefetch, one-shot frag reads,
// single barrier/K-tile, st_16x32 swizzle both-sides, zc = bid % KC XCD pinning.
__global__ __launch_bounds__(512, 2) void gemm8_kernel(const bf16_t* __restrict__ A,
                                                       const bf16_t* __restrict__ Bt,
                                                       bf16_t* __restrict__ partial,
                                                       int K, int kLen, int KC) {
  __shared__ __align__(16) bf16_t lds[4 * 2 * 2 * 128 * 32];  // 128 KiB
  const int t = threadIdx.x;
  const int lane = t & 63;
  const int w = t >> 6;         // 0..7
  const int wm = w >> 2;        // 0..1
  const int wn = w & 3;         // 0..3
  const int bid = blockIdx.x;
  const int zc = bid % KC;
  const int inner = bid / KC;   // 0..31
  const int row0 = (inner >> 2) * 256;
  const int col0 = (inner & 3) * 256;
  const int kOff = zc * kLen;
  const int G = kLen >> 5;

  const int lr = lane & 15;
  const int kb = (lane >> 4) * 16;
  int aoff[8], boff[4];
#pragma unroll
  for (int m = 0; m < 8; ++m) {
    int r = m * 16 + lr;
    aoff[m] = (r * 64 + kb) ^ (((r >> 3) & 1) << 5);
  }
#pragma unroll
  for (int n = 0; n < 4; ++n) {
    int r = (wn & 1) * 64 + n * 16 + lr;
    boff[n] = (r * 64 + kb) ^ (((r >> 3) & 1) << 5);
  }

  const int s_row = t >> 2;
  const int s_k8 = (t & 3) ^ (((s_row >> 3) & 1) << 1);
  const bf16_t* pAs = A + (size_t)(row0 + s_row) * K + kOff + s_k8 * 8;
  const bf16_t* pBs = Bt + (size_t)(col0 + s_row) * K + kOff + s_k8 * 8;
  const size_t halfStride = (size_t)128 * K;
  char* ldsBase = (char*)&lds[0];
  const int wOff = w << 10;

  auto stage = [&](int buf, int hp, int kt) {
    const bf16_t* src = ((hp < 2) ? pAs : pBs) + (size_t)(hp & 1) * halfStride + kt * 32;
    char* dst = ldsBase + buf * 32768 + (hp >> 1) * 16384 + (hp & 1) * 8192 + wOff;
    gload16(src, dst);
  };

  f32x4 acc[8][4] = {};

#pragma unroll
  for (int hp = 0; hp < 4; ++hp) stage(0, hp, 0);
#pragma unroll
  for (int hp = 0; hp < 4; ++hp) stage(1, hp, 1);
#pragma unroll
  for (int hp = 0; hp < 4; ++hp) stage(2, hp, 2);
  asm volatile("s_waitcnt vmcnt(8)" ::: "memory");
  __builtin_amdgcn_s_barrier();
  __builtin_amdgcn_sched_barrier(0);

  for (int g = 0; g < G; ++g) {
    const int cb = g & 3;
    const int sb = (g + 3) & 3;
    const bool doStage = (g + 3) < G;
    if (doStage) {
#pragma unroll
      for (int hp = 0; hp < 4; ++hp) stage(sb, hp, g + 3);
    }
    char* lA = ldsBase + cb * 32768 + wm * 8192;
    char* lB = ldsBase + cb * 32768 + 16384 + (wn >> 1) * 8192;
    bf16x8 af[8], bfv[4];
#pragma unroll
    for (int i = 0; i < 8; ++i) af[i] = *(const bf16x8*)(lA + aoff[i]);
#pragma unroll
    for (int j2 = 0; j2 < 4; ++j2) bfv[j2] = *(const bf16x8*)(lB + boff[j2]);
    asm volatile("s_waitcnt lgkmcnt(0)" ::: "memory");
    if (doStage)          asm volatile("s_waitcnt vmcnt(8)" ::: "memory");
    else if (g == G - 3)  asm volatile("s_waitcnt vmcnt(4)" ::: "memory");
    else                  asm volatile("s_waitcnt vmcnt(0)" ::: "memory");
    __builtin_amdgcn_sched_barrier(0);
    __builtin_amdgcn_s_barrier();
    __builtin_amdgcn_sched_barrier(0);
    __builtin_amdgcn_s_setprio(1);
#pragma unroll
    for (int i = 0; i < 8; ++i)
#pragma unroll
      for (int j2 = 0; j2 < 4; ++j2)
        acc[i][j2] = __builtin_amdgcn_mfma_f32_16x16x32_bf16(af[i], bfv[j2], acc[i][j2], 0, 0, 0);
    __builtin_amdgcn_s_setprio(0);
    __builtin_amdgcn_sched_barrier(0);
  }

  bf16_t* out = partial + (size_t)zc * MPAD * REP_;
  const int crow = (lane >> 4) * 4;
#pragma unroll
  for (int n = 0; n < 4; ++n) {
    const int col = col0 + wn * 64 + n * 16 + lr;
#pragma unroll
    for (int m = 0; m < 8; ++m) {
      const int rowb = row0 + wm * 128 + m * 16 + crow;
#pragma unroll
      for (int j2 = 0; j2 < 4; ++j2)
        out[(size_t)(rowb + j2) * REP_ + col] = (bf16_t)acc[m][n][j2];
    }
  }
}

// ---------------- FC2/FC3: 128x128-tile deep-pipelined GEMM (4-wave, split-K) ----------------
// Direct geometry port of gemm8's proven schedule: 4 issues/K-tile (same vmcnt ladder),
// 4 LDS buffers x 16KB = 64KB (2 blocks/CU), same swizzle involution, XCD pinning.
// Requires G = kLen/32 >= 3.
template <typename OT>
__global__ __launch_bounds__(256, 2) void gemm128_kernel(const bf16_t* __restrict__ A,
                                                         const bf16_t* __restrict__ Bt,
                                                         OT* __restrict__ partial,
                                                         int K, int kLen, int KC,
                                                         int GN, int ldc) {
  __shared__ __align__(16) bf16_t lds[4 * 2 * 128 * 32];  // 64 KiB
  const int t = threadIdx.x;
  const int lane = t & 63;
  const int w = t >> 6;         // 0..3
  const int wm = w >> 1;        // 0..1
  const int wn = w & 1;         // 0..1
  const int bid = blockIdx.x;
  const int zc = bid % KC;
  const int inner = bid / KC;
  const int row0 = (inner / GN) * 128;
  const int col0 = (inner % GN) * 128;
  const int kOff = zc * kLen;
  const int G = kLen >> 5;      // >= 3

  const int lr = lane & 15;
  const int kb = (lane >> 4) * 16;
  int aoff[4], boff[4];
#pragma unroll
  for (int m = 0; m < 4; ++m) {
    int r = wm * 64 + m * 16 + lr;
    aoff[m] = (r * 64 + kb) ^ (((r >> 3) & 1) << 5);
  }
#pragma unroll
  for (int n = 0; n < 4; ++n) {
    int r = wn * 64 + n * 16 + lr;
    boff[n] = (r * 64 + kb) ^ (((r >> 3) & 1) << 5);
  }

  const int s_row = t >> 2;                                // 0..63
  const int s_k8 = (t & 3) ^ (((s_row >> 3) & 1) << 1);    // bit3 invariant under +64
  const bf16_t* pAs = A + (size_t)(row0 + s_row) * K + kOff + s_k8 * 8;
  const bf16_t* pBs = Bt + (size_t)(col0 + s_row) * K + kOff + s_k8 * 8;
  const size_t halfStride = (size_t)64 * K;                // rows 64..127 of the tile
  char* ldsBase = (char*)&lds[0];
  const int wOff = w << 10;

  // hp: 0=A rows 0-63, 1=A rows 64-127, 2=B rows 0-63, 3=B rows 64-127
  auto stage = [&](int buf, int hp, int kt) {
    const bf16_t* src = ((hp < 2) ? pAs : pBs) + (size_t)(hp & 1) * halfStride + kt * 32;
    char* dst = ldsBase + buf * 16384 + (hp >> 1) * 8192 + (hp & 1) * 4096 + wOff;
    gload16(src, dst);
  };

  f32x4 acc[4][4] = {};

#pragma unroll
  for (int hp = 0; hp < 4; ++hp) stage(0, hp, 0);
#pragma unroll
  for (int hp = 0; hp < 4; ++hp) stage(1, hp, 1);
#pragma unroll
  for (int hp = 0; hp < 4; ++hp) stage(2, hp, 2);
  asm volatile("s_waitcnt vmcnt(8)" ::: "memory");
  __builtin_amdgcn_s_barrier();
  __builtin_amdgcn_sched_barrier(0);

  for (int g = 0; g < G; ++g) {
    const int cb = g & 3;
    const int sb = (g + 3) & 3;
    const bool doStage = (g + 3) < G;
    if (doStage) {
#pragma unroll
      for (int hp = 0; hp < 4; ++hp) stage(sb, hp, g + 3);
    }
    char* lA = ldsBase + cb * 16384;          // A tile [128][32] swizzled
    char* lB = ldsBase + cb * 16384 + 8192;   // B tile [128][32] swizzled
    bf16x8 af[4], bfv[4];
#pragma unroll
    for (int i = 0; i < 4; ++i) af[i] = *(const bf16x8*)(lA + aoff[i]);
#pragma unroll
    for (int j2 = 0; j2 < 4; ++j2) bfv[j2] = *(const bf16x8*)(lB + boff[j2]);
    asm volatile("s_waitcnt lgkmcnt(0)" ::: "memory");
    if (doStage)          asm volatile("s_waitcnt vmcnt(8)" ::: "memory");
    else if (g == G - 3)  asm volatile("s_waitcnt vmcnt(4)" ::: "memory");
    else                  asm volatile("s_waitcnt vmcnt(0)" ::: "memory");
    __builtin_amdgcn_sched_barrier(0);
    __builtin_amdgcn_s_barrier();
    __builtin_amdgcn_sched_barrier(0);
    __builtin_amdgcn_s_setprio(1);
#pragma unroll
    for (int i = 0; i < 4; ++i)
#pragma unroll
      for (int j2 = 0; j2 < 4; ++j2)
        acc[i][j2] = __builtin_amdgcn_mfma_f32_16x16x32_bf16(af[i], bfv[j2], acc[i][j2], 0, 0, 0);
    __builtin_amdgcn_s_setprio(0);
    __builtin_amdgcn_sched_barrier(0);
  }

  OT* out = partial + (size_t)zc * MPAD * ldc;
  const int crow = (lane >> 4) * 4;
#pragma unroll
  for (int n = 0; n < 4; ++n) {
    const int col = col0 + wn * 64 + n * 16 + lr;
#pragma unroll
    for (int m = 0; m < 4; ++m) {
      const int rowb = row0 + wm * 64 + m * 16 + crow;
#pragma unroll
      for (int j2 = 0; j2 < 4; ++j2)
        out[(size_t)(rowb + j2) * ldc + col] = (OT)acc[m][n][j2];
    }
  }
}

// ---------------- bf16 split-K reduce: out = relu(sum + bias) -> bf16 (8/thread, ldc=REP_) ----
__global__ __launch_bounds__(256) void reduceH_kernel(const bf16_t* __restrict__ partial,
                                                      const float* __restrict__ bias,
                                                      bf16_t* __restrict__ out,
                                                      int KC) {
  const size_t idx8 = ((size_t)blockIdx.x * 256 + threadIdx.x) * 8;
  const size_t stride = (size_t)MPAD * REP_;
  float s[8] = {};
  for (int c = 0; c < KC; ++c) {
    const bf16x8 v = *(const bf16x8*)(partial + c * stride + idx8);
#pragma unroll
    for (int j = 0; j < 8; ++j) s[j] += (float)v[j];
  }
  const int col = (int)(idx8 & (size_t)(REP_ - 1));
  const f32x4 b0 = *(const f32x4*)(bias + col);
  const f32x4 b1 = *(const f32x4*)(bias + col + 4);
  bf16x8 o;
#pragma unroll
  for (int j = 0; j < 4; ++j) o[j] = (bf16_t)fmaxf(s[j] + b0[j], 0.0f);
#pragma unroll
  for (int j = 0; j < 4; ++j) o[4 + j] = (bf16_t)fmaxf(s[4 + j] + b1[j], 0.0f);
  *(bf16x8*)(out + idx8) = o;
}

// ---------------- f32 split-K reduce: out = sum + bias (f32) ----------------
__global__ __launch_bounds__(256) void reduce_kernel(const float* __restrict__ partial,
                                                     const float* __restrict__ bias,
                                                     float* __restrict__ out,
                                                     int ldc, int KC) {
  const size_t idx4 = ((size_t)blockIdx.x * 256 + threadIdx.x) * 4;
  f32x4 s = *(const f32x4*)(partial + idx4);
  const size_t stride = (size_t)MPAD * ldc;
  for (int c = 1; c < KC; ++c) s += *(const f32x4*)(partial + c * stride + idx4);
  const int col = (int)(idx4 & (size_t)(ldc - 1));
  s += *(const f32x4*)(bias + col);
  *(f32x4*)(out + idx4) = s;
}

// ---------------- row softmax stats: one wave per row ----------------
__global__ __launch_bounds__(256) void rowsm_kernel(const float* __restrict__ ho,
                                                    float* __restrict__ mxv,
                                                    float* __restrict__ invv) {
  const int row = blockIdx.x * 4 + (threadIdx.x >> 6);
  const int lane = threadIdx.x & 63;
  if (row >= M_) return;
  const float* r = ho + (size_t)row * HOUT;
  float v1 = (lane < NCLS) ? r[lane] : -3.0e38f;
  float v2 = (lane + 64 < NCLS) ? r[lane + 64] : -3.0e38f;
  float mx = fmaxf(v1, v2);
#pragma unroll
  for (int off = 32; off; off >>= 1) mx = fmaxf(mx, __shfl_xor(mx, off));
  float s = ((lane < NCLS) ? expf(v1 - mx) : 0.0f) + ((lane + 64 < NCLS) ? expf(v2 - mx) : 0.0f);
#pragma unroll
  for (int off = 32; off; off >>= 1) s += __shfl_xor(s, off);
  if (lane == 0) { mxv[row] = mx; invv[row] = 1.0f / s; }
}

// ---------------- decode + NMS prep: one thread per (roi, class) ----------------
__global__ __launch_bounds__(256) void decode_kernel(const float* __restrict__ ho,
                                                     const float* __restrict__ mxv,
                                                     const float* __restrict__ invv,
                                                     const float* __restrict__ props,
                                                     float* __restrict__ boxes,
                                                     float* __restrict__ scores,
                                                     float* __restrict__ swork,
                                                     float* __restrict__ boff,
                                                     float* __restrict__ area) {
  const int idx = blockIdx.x * 256 + threadIdx.x;
  if (idx >= M_ * 90) return;
  const int n = idx / 90;
  const int k = idx - n * 90 + 1;
  const float* row = ho + (size_t)n * HOUT;
  const float sc = expf(row[k] - mxv[n]) * invv[n];
  const float* p = props + n * 4;
  const float px1 = p[0], py1 = p[1], px2 = p[2], py2 = p[3];
  const float pw = px2 - px1, ph = py2 - py1;
  const float pcx = px1 + 0.5f * pw, pcy = py1 + 0.5f * ph;
  const float* d = row + NCLS + 4 * k;
  const float dx = d[0] * 0.1f;
  const float dy = d[1] * 0.1f;
  const float dw = fminf(d[2] * 0.2f, BBOX_CLIPF);
  const float dh = fminf(d[3] * 0.2f, BBOX_CLIPF);
  const float cx = dx * pw + pcx, cy = dy * ph + pcy;
  const float w = pw * expf(dw), h = ph * expf(dh);
  const float bx1 = fminf(fmaxf(cx - 0.5f * w, 0.0f), IMGF);
  const float by1 = fminf(fmaxf(cy - 0.5f * h, 0.0f), IMGF);
  const float bx2 = fminf(fmaxf(cx + 0.5f * w, 0.0f), IMGF);
  const float by2 = fminf(fmaxf(cy + 0.5f * h, 0.0f), IMGF);
  const int j = idx;
  boxes[4 * j + 0] = bx1; boxes[4 * j + 1] = by1;
  boxes[4 * j + 2] = bx2; boxes[4 * j + 3] = by2;
  scores[j] = sc;
  const float wv = bx2 - bx1, hv = by2 - by1;
  swork[j] = ((sc > 0.05f) && (wv >= 1.0f) && (hv >= 1.0f)) ? sc : NEGV;
  const float off = (float)k * (IMGF + 2.0f);
  const float ox1 = bx1 + off, oy1 = by1 + off, ox2 = bx2 + off, oy2 = by2 + off;
  boff[4 * j + 0] = ox1; boff[4 * j + 1] = oy1;
  boff[4 * j + 2] = ox2; boff[4 * j + 3] = oy2;
  area[j] = (ox2 - ox1) * (oy2 - oy1);
}

// ---------------- NMS: replicates jax.lax.scan semantics exactly ----------------
__global__ __launch_bounds__(1024) void nms_kernel(const float* __restrict__ boxes,
                                                   const float* __restrict__ scores,
                                                   float* __restrict__ swork,
                                                   const float* __restrict__ boff,
                                                   const float* __restrict__ area,
                                                   float* __restrict__ dout) {
  const int b = blockIdx.x;
  const int t = threadIdx.x;
  const float* Bx = boxes + (size_t)b * NMSM * 4;
  const float* Sc = scores + (size_t)b * NMSM;
  float* Sw = swork + (size_t)b * NMSM;
  const float* Bo = boff + (size_t)b * NMSM * 4;
  const float* Ar = area + (size_t)b * NMSM;
  float* dets = dout + b * (DET_ * 5);
  float* labels = dout + B_ * DET_ * 5 + b * DET_;
  __shared__ float s_val[1024];
  __shared__ int s_idx[1024];
  __shared__ float s_box[4];
  __shared__ float s_area;
  __shared__ int s_ok;
  for (int it = 0; it < DET_; ++it) {
    float bv = -3.0e38f;
    int bi = 0;
    for (int j = t; j < NMSM; j += 1024) {
      float v = Sw[j];
      if (v > bv) { bv = v; bi = j; }
    }
    s_val[t] = bv;
    s_idx[t] = bi;
    __syncthreads();
    for (int off = 512; off > 0; off >>= 1) {
      if (t < off) {
        float v2 = s_val[t + off]; int i2 = s_idx[t + off];
        if (v2 > s_val[t] || (v2 == s_val[t] && i2 < s_idx[t])) { s_val[t] = v2; s_idx[t] = i2; }
      }
      __syncthreads();
    }
    if (t == 0) {
      int i = s_idx[0];
      int ok = (s_val[0] > NEGV * 0.5f) ? 1 : 0;
      s_ok = ok;
      if (ok) {
        dets[it * 5 + 0] = Bx[i * 4 + 0];
        dets[it * 5 + 1] = Bx[i * 4 + 1];
        dets[it * 5 + 2] = Bx[i * 4 + 2];
        dets[it * 5 + 3] = Bx[i * 4 + 3];
        dets[it * 5 + 4] = Sc[i];
        labels[it] = (float)(i % 90 + 1);
        s_box[0] = Bo[i * 4 + 0]; s_box[1] = Bo[i * 4 + 1];
        s_box[2] = Bo[i * 4 + 2]; s_box[3] = Bo[i * 4 + 3];
        s_area = Ar[i];
        Sw[i] = NEGV;
      }
    }
    __syncthreads();
    if (!s_ok) {
      for (int tt = it + t; tt < DET_; tt += 1024) {
        dets[tt * 5 + 0] = 0.0f; dets[tt * 5 + 1] = 0.0f; dets[tt * 5 + 2] = 0.0f;
        dets[tt * 5 + 3] = 0.0f; dets[tt * 5 + 4] = 0.0f;
        labels[tt] = -1.0f;
      }
      return;
    }
    const float bx1 = s_box[0], by1 = s_box[1], bx2 = s_box[2], by2 = s_box[3], ai = s_area;
    for (int j = t; j < NMSM; j += 1024) {
      float v = Sw[j];
      if (v <= NEGV * 0.5f) continue;
      float ix1 = fmaxf(bx1, Bo[j * 4 + 0]);
      float iy1 = fmaxf(by1, Bo[j * 4 + 1]);
      float ix2 = fminf(bx2, Bo[j * 4 + 2]);
      float iy2 = fminf(by2, Bo[j * 4 + 3]);
      float inter = fmaxf(ix2 - ix1, 0.0f) * fmaxf(iy2 - iy1, 0.0f);
      float iou = inter / (ai + Ar[j] - inter + 1e-9f);
      if (iou > 0.5f) Sw[j] = NEGV;
    }
    __syncthreads();
  }
}

// ---------------- launch ----------------
extern "C" void kernel_launch(void* const* d_in, const int* in_sizes, int n_in,
                              void* d_out, int out_size, void* d_ws, size_t ws_size,
                              hipStream_t stream) {
  const float* features  = (const float*)d_in[0];
  const float* proposals = (const float*)d_in[1];
  const float* w1   = (const float*)d_in[2];
  const float* b1   = (const float*)d_in[3];
  const float* w2   = (const float*)d_in[4];
  const float* b2   = (const float*)d_in[5];
  const float* wcls = (const float*)d_in[6];
  const float* bcls = (const float*)d_in[7];
  const float* wbb  = (const float*)d_in[8];
  const float* bbb  = (const float*)d_in[9];
  (void)in_sizes; (void)n_in; (void)out_size;

  char* p = (char*)d_ws;
  auto alloc = [&](size_t bytes) {
    char* r = p;
    p += (bytes + 255) & ~(size_t)255;
    return r;
  };
  bf16_t* A      = (bf16_t*)alloc((size_t)MPAD * DIN * 2);
  bf16_t* w1t    = (bf16_t*)alloc((size_t)REP_ * DIN * 2);
  bf16_t* w2t    = (bf16_t*)alloc((size_t)REP_ * REP_ * 2);
  bf16_t* wht    = (bf16_t*)alloc((size_t)HOUT * REP_ * 2);
  float*  biash  = (float*)alloc((size_t)HOUT * 4);
  bf16_t* h1     = (bf16_t*)alloc((size_t)MPAD * REP_ * 2);
  bf16_t* h2     = (bf16_t*)alloc((size_t)MPAD * REP_ * 2);
  float*  ho     = (float*)alloc((size_t)MPAD * HOUT * 4);
  float*  mxv    = (float*)alloc((size_t)M_ * 4);
  float*  invv   = (float*)alloc((size_t)M_ * 4);
  float*  boxes  = (float*)alloc((size_t)B_ * NMSM * 4 * 4);
  float*  scoresb= (float*)alloc((size_t)B_ * NMSM * 4);
  float*  sworkb = (float*)alloc((size_t)B_ * NMSM * 4);
  float*  boffb  = (float*)alloc((size_t)B_ * NMSM * 4 * 4);
  float*  areab  = (float*)alloc((size_t)B_ * NMSM * 4);

  size_t used = (size_t)(p - (char*)d_ws);
  size_t avail = (ws_size > used) ? (ws_size - used) : 0;
  bf16_t* partialH = (bf16_t*)p;   // bf16 partials (FC1/FC2)
  float*  partialF = (float*)p;    // f32 partials (FC3, stream-ordered reuse)
  const size_t chunkH = (size_t)MPAD * REP_ * 2;   // 4 MB
  const size_t chunkF = (size_t)MPAD * HOUT * 4;   // 4 MB
  int KC1 = 8;   // kLen = 1568, G = 49
  while (KC1 > 1 && (size_t)KC1 * chunkH > avail) KC1 >>= 1;
  int KC2 = 2;   // kLen = 512, G = 16; 128 tiles x 2 = 256 blocks
  while (KC2 > 1 && (size_t)KC2 * chunkH > avail) KC2 >>= 1;
  int KC3 = 4;   // kLen = 256, G = 8; 64 tiles x 4 = 256 blocks
  while (KC3 > 1 && (size_t)KC3 * chunkF > avail) KC3 >>= 1;

  // prep before roi: weight writebacks drain under roi
  transpose_kernel<<<dim3(DIN / 32, REP_ / 32), 256, 0, stream>>>(w1, w1t, DIN, REP_);
  transpose_kernel<<<dim3(REP_ / 32, REP_ / 32), 256, 0, stream>>>(w2, w2t, REP_, REP_);
  headw_kernel<<<(HOUT * REP_) / 256, 256, 0, stream>>>(wcls, wbb, wht);
  headb_kernel<<<1, HOUT, 0, stream>>>(bcls, bbb, biash);
  roi_kernel<<<dim3(C_ / CC_, (MPAD + RC_ - 1) / RC_), 256, 0, stream>>>(features, proposals, A);

  // FC1: [2048 x 12544] @ [12544 x 1024] -> h1 (relu, bf16). 8-wave depth-3 pipeline.
  gemm8_kernel<<<32 * KC1, 512, 0, stream>>>(A, w1t, partialH, DIN, DIN / KC1, KC1);
  reduceH_kernel<<<(MPAD * REP_ / 8) / 256, 256, 0, stream>>>(partialH, b1, h1, KC1);
  // FC2: [2048 x 1024] @ [1024 x 1024] -> h2 (relu, bf16). 4-wave 128-tile pipeline, KC=2.
  gemm128_kernel<bf16_t><<<(MPAD / 128) * (REP_ / 128) * KC2, 256, 0, stream>>>(
      h1, w2t, partialH, REP_, REP_ / KC2, KC2, REP_ / 128, REP_);
  reduceH_kernel<<<(MPAD * REP_ / 8) / 256, 256, 0, stream>>>(partialH, b2, h2, KC2);
  // FC3 (heads): [2048 x 1024] @ [1024 x 512] -> ho (f32). 4-wave 128-tile pipeline, KC=4.
  gemm128_kernel<float><<<(MPAD / 128) * (HOUT / 128) * KC3, 256, 0, stream>>>(
      h2, wht, partialF, REP_, REP_ / KC3, KC3, HOUT / 128, HOUT);
  reduce_kernel<<<(MPAD * HOUT / 4) / 256, 256, 0, stream>>>(partialF, biash, ho, HOUT, KC3);

  rowsm_kernel<<<(M_ + 3) / 4, 256, 0, stream>>>(ho, mxv, invv);
  decode_kernel<<<(M_ * 90 + 255) / 256, 256, 0, stream>>>(ho, mxv, invv, proposals,
                                                           boxes, scoresb, sworkb, boffb, areab);
  nms_kernel<<<B_, 1024, 0, stream>>>(boxes, scoresb, sworkb, boffb, areab, (float*)d_out);
}

// Round 15
// 175.902 us; speedup vs baseline: 1.2028x; 1.0410x over previous
//
#include <hip/hip_runtime.h>
#include <stdint.h>

// ---------------- problem constants (hard-coded from reference) ----------------
#define B_    2
#define N_    1000
#define C_    256
#define H_    50
#define W_    50
#define P_    7
#define NCLS  91
#define REP_  1024
#define DIN   (C_ * P_ * P_)   // 12544
#define M_    (B_ * N_)        // 2000
#define MPAD  2048
#define HOUT  512              // padded head cols (91 cls + 364 bbox = 455 real)
#define DET_  100
#define NMSM  (N_ * 90)        // 90000 candidates per batch
#define NEGV  (-1000000000.0f)
#define SCALE_ 0.0625f
#define IMGF  800.0f
#define BBOX_CLIPF 4.135166556742356f  // log(1000/16)

#define RC_   25               // rois per roi-chunk (1000 % 25 == 0: no batch mixing)
#define CC_   4                // channels per channel-chunk
#define NROIB ((C_ / CC_) * ((MPAD + RC_ - 1) / RC_))   // 64*82 = 5248
#define NW1B  ((DIN / 32) * (REP_ / 32))    // 12544
#define NW2B  ((REP_ / 32) * (REP_ / 32))   // 1024
#define NHWB  ((HOUT * REP_) / 256)         // 2048

typedef __bf16 bf16_t;
typedef __attribute__((ext_vector_type(8))) __bf16 bf16x8;
typedef __attribute__((ext_vector_type(4))) __bf16 bf16x4;
typedef __attribute__((ext_vector_type(4))) float f32x4;

// async global->LDS, 16B per lane. LDS dest must be wave-uniform base (+lane*16 by HW).
__device__ __forceinline__ void gload16(const void* g, void* l) {
  auto gp = (const __attribute__((address_space(1))) uint32_t*)(uintptr_t)g;
  auto lp = (__attribute__((address_space(3))) uint32_t*)(uint32_t)(uintptr_t)l;
  __builtin_amdgcn_global_load_lds(gp, lp, 16, 0, 0);
}

// ---------------- fused pre: ROI align + w1^T/w2^T transpose + head weight/bias ----------------
// One launch; disjoint blockIdx ranges; 52.3KB LDS carve reused per branch.
// roi: LDS-staged feature planes, gathers from LDS (R7-proven). transpose: R11-proven.
__global__ __launch_bounds__(256) void fused_pre_kernel(const float* __restrict__ features,
                                                        const float* __restrict__ proposals,
                                                        const float* __restrict__ w1,
                                                        const float* __restrict__ w2,
                                                        const float* __restrict__ wcls,
                                                        const float* __restrict__ wbb,
                                                        const float* __restrict__ bcls,
                                                        const float* __restrict__ bbb,
                                                        bf16_t* __restrict__ A,
                                                        bf16_t* __restrict__ w1t,
                                                        bf16_t* __restrict__ w2t,
                                                        bf16_t* __restrict__ wht,
                                                        float* __restrict__ biash) {
  __shared__ __align__(16) char smem[52256];
  int bidx = blockIdx.x;
  const int t = threadIdx.x;

  if (bidx < NROIB) {
    // ---------------- ROI align branch ----------------
    const int cc0 = (bidx & 63) * CC_;       // channel base
    const int roiBase = (bidx >> 6) * RC_;   // roi base
    if (roiBase >= M_) {
      for (int idx = t; idx < RC_ * 49; idx += 256) {
        const int r = idx / 49, pp = idx - r * 49;
        const int n = roiBase + r;
        if (n < MPAD) {
          bf16_t* arow = A + (size_t)n * DIN + cc0 * 49 + pp;
#pragma unroll
          for (int c = 0; c < CC_; ++c) arow[c * 49] = (bf16_t)0.0f;
        }
      }
      return;
    }
    float* s_pl = (float*)smem;                               // 40000 B
    float* s_ly = (float*)(smem + 40000);                     // 4900 B
    float* s_lx = (float*)(smem + 44900);                     // 4900 B
    unsigned short* s_off = (unsigned short*)(smem + 49800);  // 2450 B
    const int b = (roiBase >= N_) ? 1 : 0;
    const f32x4* src = (const f32x4*)(features + (size_t)(b * C_ + cc0) * (H_ * W_));
    f32x4* dst = (f32x4*)s_pl;
    for (int i = t; i < CC_ * 2500 / 4; i += 256) dst[i] = src[i];
    for (int idx = t; idx < RC_ * 49; idx += 256) {
      const int r = idx / 49, pp = idx - r * 49;
      const int py = pp / 7, px = pp - py * 7;
      const float* p = proposals + (roiBase + r) * 4;
      float y1 = p[1] * SCALE_, y2 = p[3] * SCALE_;
      float bh = (y2 - y1) * (1.0f / 7.0f);
      float y = y1 + ((float)py + 0.5f) * bh - 0.5f;
      y = fminf(fmaxf(y, 0.0f), 49.0f);
      int y0 = (int)floorf(y);
      int dy = (y0 < 49) ? 1 : 0;
      float ly = y - (float)y0;
      float x1 = p[0] * SCALE_, x2 = p[2] * SCALE_;
      float bw = (x2 - x1) * (1.0f / 7.0f);
      float x = x1 + ((float)px + 0.5f) * bw - 0.5f;
      x = fminf(fmaxf(x, 0.0f), 49.0f);
      int x0 = (int)floorf(x);
      int dx = (x0 < 49) ? 1 : 0;
      float lx = x - (float)x0;
      s_off[idx] = (unsigned short)((y0 * W_ + x0) | (dx << 12) | (dy << 13));
      s_ly[idx] = ly;
      s_lx[idx] = lx;
    }
    __syncthreads();
    for (int idx = t; idx < RC_ * 49; idx += 256) {
      const int r = idx / 49, pp = idx - r * 49;
      const unsigned off = s_off[idx];
      const float ly = s_ly[idx], lx = s_lx[idx];
      const float hy = 1.0f - ly, hx = 1.0f - lx;
      const int o00 = off & 0xFFF;
      const int dx = (off >> 12) & 1;
      const int o10 = o00 + W_ * ((off >> 13) & 1);
      const float w00 = hy * hx, w01 = hy * lx, w10 = ly * hx, w11 = ly * lx;
      bf16_t* arow = A + (size_t)(roiBase + r) * DIN + cc0 * 49 + pp;
#pragma unroll
      for (int c = 0; c < CC_; ++c) {
        const float* pl = s_pl + c * 2500;
        float v = pl[o00] * w00 + pl[o00 + dx] * w01 + pl[o10] * w10 + pl[o10 + dx] * w11;
        arow[c * 49] = (bf16_t)v;
      }
    }
    return;
  }
  bidx -= NROIB;

  if (bidx < NW1B + NW2B) {
    // ---------------- transpose+convert branch: f32 [K][N] -> bf16 [N][K] ----------------
    float* tile = (float*)smem;  // [32][33]
    const float* in;
    bf16_t* out;
    int K, N, kbk, nbk;
    if (bidx < NW1B) {
      in = w1; out = w1t; K = DIN; N = REP_;
      kbk = bidx % (DIN / 32); nbk = bidx / (DIN / 32);
    } else {
      bidx -= NW1B;
      in = w2; out = w2t; K = REP_; N = REP_;
      kbk = bidx % (REP_ / 32); nbk = bidx / (REP_ / 32);
    }
    const int k0 = kbk * 32, n0 = nbk * 32;
    const int tx = t & 31;
    const int ty = t >> 5;
#pragma unroll
    for (int j = 0; j < 4; ++j) {
      int ky = ty + j * 8;
      tile[ky * 33 + tx] = in[(size_t)(k0 + ky) * N + n0 + tx];
    }
    __syncthreads();
    const int qx = t & 7;
    const int ny = t >> 3;
    bf16x4 o;
#pragma unroll
    for (int i = 0; i < 4; ++i) o[i] = (bf16_t)tile[(4 * qx + i) * 33 + ny];
    *(bf16x4*)(&out[(size_t)(n0 + ny) * K + k0 + 4 * qx]) = o;
  } else if (bidx < NW1B + NW2B + NHWB) {
    // ---------------- head weight concat ----------------
    int idx = (bidx - NW1B - NW2B) * 256 + t;
    int j = idx >> 10;
    int k = idx & 1023;
    float v = 0.0f;
    if (j < NCLS) v = wcls[(size_t)k * NCLS + j];
    else if (j < 455) v = wbb[(size_t)k * 364 + (j - NCLS)];
    wht[idx] = (bf16_t)v;
  } else {
    // ---------------- head bias ----------------
    for (int j = t; j < HOUT; j += 256) {
      float v = 0.0f;
      if (j < NCLS) v = bcls[j];
      else if (j < 455) v = bbb[j - NCLS];
      biash[j] = v;
    }
  }
}

// ---------------- FC1: 256x256-tile deep-pipelined MFMA GEMM (8-wave, split-K) ----------------
// [R9-proven: 57us] 4 LDS buffers (128 KiB), depth-3 prefetch, one-shot frag reads,
// single barrier/K-tile, st_16x32 swizzle both-sides, zc = bid % KC XCD pinning.
__global__ __launch_bounds__(512, 2) void gemm8_kernel(const bf16_t* __restrict__ A,
                                                       const bf16_t* __restrict__ Bt,
                                                       bf16_t* __restrict__ partial,
                                                       int K, int kLen, int KC) {
  __shared__ __align__(16) bf16_t lds[4 * 2 * 2 * 128 * 32];  // 128 KiB
  const int t = threadIdx.x;
  const int lane = t & 63;
  const int w = t >> 6;         // 0..7
  const int wm = w >> 2;        // 0..1
  const int wn = w & 3;         // 0..3
  const int bid = blockIdx.x;
  const int zc = bid % KC;
  const int inner = bid / KC;   // 0..31
  const int row0 = (inner >> 2) * 256;
  const int col0 = (inner & 3) * 256;
  const int kOff = zc * kLen;
  const int G = kLen >> 5;

  const int lr = lane & 15;
  const int kb = (lane >> 4) * 16;
  int aoff[8], boff[4];
#pragma unroll
  for (int m = 0; m < 8; ++m) {
    int r = m * 16 + lr;
    aoff[m] = (r * 64 + kb) ^ (((r >> 3) & 1) << 5);
  }
#pragma unroll
  for (int n = 0; n < 4; ++n) {
    int r = (wn & 1) * 64 + n * 16 + lr;
    boff[n] = (r * 64 + kb) ^ (((r >> 3) & 1) << 5);
  }

  const int s_row = t >> 2;
  const int s_k8 = (t & 3) ^ (((s_row >> 3) & 1) << 1);
  const bf16_t* pAs = A + (size_t)(row0 + s_row) * K + kOff + s_k8 * 8;
  const bf16_t* pBs = Bt + (size_t)(col0 + s_row) * K + kOff + s_k8 * 8;
  const size_t halfStride = (size_t)128 * K;
  char* ldsBase = (char*)&lds[0];
  const int wOff = w << 10;

  auto stage = [&](int buf, int hp, int kt) {
    const bf16_t* src = ((hp < 2) ? pAs : pBs) + (size_t)(hp & 1) * halfStride + kt * 32;
    char* dst = ldsBase + buf * 32768 + (hp >> 1) * 16384 + (hp & 1) * 8192 + wOff;
    gload16(src, dst);
  };

  f32x4 acc[8][4] = {};

#pragma unroll
  for (int hp = 0; hp < 4; ++hp) stage(0, hp, 0);
#pragma unroll
  for (int hp = 0; hp < 4; ++hp) stage(1, hp, 1);
#pragma unroll
  for (int hp = 0; hp < 4; ++hp) stage(2, hp, 2);
  asm volatile("s_waitcnt vmcnt(8)" ::: "memory");
  __builtin_amdgcn_s_barrier();
  __builtin_amdgcn_sched_barrier(0);

  for (int g = 0; g < G; ++g) {
    const int cb = g & 3;
    const int sb = (g + 3) & 3;
    const bool doStage = (g + 3) < G;
    if (doStage) {
#pragma unroll
      for (int hp = 0; hp < 4; ++hp) stage(sb, hp, g + 3);
    }
    char* lA = ldsBase + cb * 32768 + wm * 8192;
    char* lB = ldsBase + cb * 32768 + 16384 + (wn >> 1) * 8192;
    bf16x8 af[8], bfv[4];
#pragma unroll
    for (int i = 0; i < 8; ++i) af[i] = *(const bf16x8*)(lA + aoff[i]);
#pragma unroll
    for (int j2 = 0; j2 < 4; ++j2) bfv[j2] = *(const bf16x8*)(lB + boff[j2]);
    asm volatile("s_waitcnt lgkmcnt(0)" ::: "memory");
    if (doStage)          asm volatile("s_waitcnt vmcnt(8)" ::: "memory");
    else if (g == G - 3)  asm volatile("s_waitcnt vmcnt(4)" ::: "memory");
    else                  asm volatile("s_waitcnt vmcnt(0)" ::: "memory");
    __builtin_amdgcn_sched_barrier(0);
    __builtin_amdgcn_s_barrier();
    __builtin_amdgcn_sched_barrier(0);
    __builtin_amdgcn_s_setprio(1);
#pragma unroll
    for (int i = 0; i < 8; ++i)
#pragma unroll
      for (int j2 = 0; j2 < 4; ++j2)
        acc[i][j2] = __builtin_amdgcn_mfma_f32_16x16x32_bf16(af[i], bfv[j2], acc[i][j2], 0, 0, 0);
    __builtin_amdgcn_s_setprio(0);
    __builtin_amdgcn_sched_barrier(0);
  }

  bf16_t* out = partial + (size_t)zc * MPAD * REP_;
  const int crow = (lane >> 4) * 4;
#pragma unroll
  for (int n = 0; n < 4; ++n) {
    const int col = col0 + wn * 64 + n * 16 + lr;
#pragma unroll
    for (int m = 0; m < 8; ++m) {
      const int rowb = row0 + wm * 128 + m * 16 + crow;
#pragma unroll
      for (int j2 = 0; j2 < 4; ++j2)
        out[(size_t)(rowb + j2) * REP_ + col] = (bf16_t)acc[m][n][j2];
    }
  }
}

// ---------------- FC2/FC3: 128x128-tile deep-pipelined GEMM (4-wave, split-K) ----------------
// [R14-proven] Geometry port of gemm8's schedule; 64KB LDS (2 blocks/CU); same swizzle.
template <typename OT>
__global__ __launch_bounds__(256, 2) void gemm128_kernel(const bf16_t* __restrict__ A,
                                                         const bf16_t* __restrict__ Bt,
                                                         OT* __restrict__ partial,
                                                         int K, int kLen, int KC,
                                                         int GN, int ldc) {
  __shared__ __align__(16) bf16_t lds[4 * 2 * 128 * 32];  // 64 KiB
  const int t = threadIdx.x;
  const int lane = t & 63;
  const int w = t >> 6;         // 0..3
  const int wm = w >> 1;        // 0..1
  const int wn = w & 1;         // 0..1
  const int bid = blockIdx.x;
  const int zc = bid % KC;
  const int inner = bid / KC;
  const int row0 = (inner / GN) * 128;
  const int col0 = (inner % GN) * 128;
  const int kOff = zc * kLen;
  const int G = kLen >> 5;      // >= 3

  const int lr = lane & 15;
  const int kb = (lane >> 4) * 16;
  int aoff[4], boff[4];
#pragma unroll
  for (int m = 0; m < 4; ++m) {
    int r = wm * 64 + m * 16 + lr;
    aoff[m] = (r * 64 + kb) ^ (((r >> 3) & 1) << 5);
  }
#pragma unroll
  for (int n = 0; n < 4; ++n) {
    int r = wn * 64 + n * 16 + lr;
    boff[n] = (r * 64 + kb) ^ (((r >> 3) & 1) << 5);
  }

  const int s_row = t >> 2;                                // 0..63
  const int s_k8 = (t & 3) ^ (((s_row >> 3) & 1) << 1);    // bit3 invariant under +64
  const bf16_t* pAs = A + (size_t)(row0 + s_row) * K + kOff + s_k8 * 8;
  const bf16_t* pBs = Bt + (size_t)(col0 + s_row) * K + kOff + s_k8 * 8;
  const size_t halfStride = (size_t)64 * K;
  char* ldsBase = (char*)&lds[0];
  const int wOff = w << 10;

  auto stage = [&](int buf, int hp, int kt) {
    const bf16_t* src = ((hp < 2) ? pAs : pBs) + (size_t)(hp & 1) * halfStride + kt * 32;
    char* dst = ldsBase + buf * 16384 + (hp >> 1) * 8192 + (hp & 1) * 4096 + wOff;
    gload16(src, dst);
  };

  f32x4 acc[4][4] = {};

#pragma unroll
  for (int hp = 0; hp < 4; ++hp) stage(0, hp, 0);
#pragma unroll
  for (int hp = 0; hp < 4; ++hp) stage(1, hp, 1);
#pragma unroll
  for (int hp = 0; hp < 4; ++hp) stage(2, hp, 2);
  asm volatile("s_waitcnt vmcnt(8)" ::: "memory");
  __builtin_amdgcn_s_barrier();
  __builtin_amdgcn_sched_barrier(0);

  for (int g = 0; g < G; ++g) {
    const int cb = g & 3;
    const int sb = (g + 3) & 3;
    const bool doStage = (g + 3) < G;
    if (doStage) {
#pragma unroll
      for (int hp = 0; hp < 4; ++hp) stage(sb, hp, g + 3);
    }
    char* lA = ldsBase + cb * 16384;
    char* lB = ldsBase + cb * 16384 + 8192;
    bf16x8 af[4], bfv[4];
#pragma unroll
    for (int i = 0; i < 4; ++i) af[i] = *(const bf16x8*)(lA + aoff[i]);
#pragma unroll
    for (int j2 = 0; j2 < 4; ++j2) bfv[j2] = *(const bf16x8*)(lB + boff[j2]);
    asm volatile("s_waitcnt lgkmcnt(0)" ::: "memory");
    if (doStage)          asm volatile("s_waitcnt vmcnt(8)" ::: "memory");
    else if (g == G - 3)  asm volatile("s_waitcnt vmcnt(4)" ::: "memory");
    else                  asm volatile("s_waitcnt vmcnt(0)" ::: "memory");
    __builtin_amdgcn_sched_barrier(0);
    __builtin_amdgcn_s_barrier();
    __builtin_amdgcn_sched_barrier(0);
    __builtin_amdgcn_s_setprio(1);
#pragma unroll
    for (int i = 0; i < 4; ++i)
#pragma unroll
      for (int j2 = 0; j2 < 4; ++j2)
        acc[i][j2] = __builtin_amdgcn_mfma_f32_16x16x32_bf16(af[i], bfv[j2], acc[i][j2], 0, 0, 0);
    __builtin_amdgcn_s_setprio(0);
    __builtin_amdgcn_sched_barrier(0);
  }

  OT* out = partial + (size_t)zc * MPAD * ldc;
  const int crow = (lane >> 4) * 4;
#pragma unroll
  for (int n = 0; n < 4; ++n) {
    const int col = col0 + wn * 64 + n * 16 + lr;
#pragma unroll
    for (int m = 0; m < 4; ++m) {
      const int rowb = row0 + wm * 64 + m * 16 + crow;
#pragma unroll
      for (int j2 = 0; j2 < 4; ++j2)
        out[(size_t)(rowb + j2) * ldc + col] = (OT)acc[m][n][j2];
    }
  }
}

// ---------------- bf16 split-K reduce: out = relu(sum + bias) -> bf16 (8/thread, ldc=REP_) ----
__global__ __launch_bounds__(256) void reduceH_kernel(const bf16_t* __restrict__ partial,
                                                      const float* __restrict__ bias,
                                                      bf16_t* __restrict__ out,
                                                      int KC) {
  const size_t idx8 = ((size_t)blockIdx.x * 256 + threadIdx.x) * 8;
  const size_t stride = (size_t)MPAD * REP_;
  float s[8] = {};
  for (int c = 0; c < KC; ++c) {
    const bf16x8 v = *(const bf16x8*)(partial + c * stride + idx8);
#pragma unroll
    for (int j = 0; j < 8; ++j) s[j] += (float)v[j];
  }
  const int col = (int)(idx8 & (size_t)(REP_ - 1));
  const f32x4 b0 = *(const f32x4*)(bias + col);
  const f32x4 b1 = *(const f32x4*)(bias + col + 4);
  bf16x8 o;
#pragma unroll
  for (int j = 0; j < 4; ++j) o[j] = (bf16_t)fmaxf(s[j] + b0[j], 0.0f);
#pragma unroll
  for (int j = 0; j < 4; ++j) o[4 + j] = (bf16_t)fmaxf(s[4 + j] + b1[j], 0.0f);
  *(bf16x8*)(out + idx8) = o;
}

// ---------------- f32 split-K reduce: out = sum + bias (f32) ----------------
__global__ __launch_bounds__(256) void reduce_kernel(const float* __restrict__ partial,
                                                     const float* __restrict__ bias,
                                                     float* __restrict__ out,
                                                     int ldc, int KC) {
  const size_t idx4 = ((size_t)blockIdx.x * 256 + threadIdx.x) * 4;
  f32x4 s = *(const f32x4*)(partial + idx4);
  const size_t stride = (size_t)MPAD * ldc;
  for (int c = 1; c < KC; ++c) s += *(const f32x4*)(partial + c * stride + idx4);
  const int col = (int)(idx4 & (size_t)(ldc - 1));
  s += *(const f32x4*)(bias + col);
  *(f32x4*)(out + idx4) = s;
}

// ---------------- row softmax stats: one wave per row ----------------
__global__ __launch_bounds__(256) void rowsm_kernel(const float* __restrict__ ho,
                                                    float* __restrict__ mxv,
                                                    float* __restrict__ invv) {
  const int row = blockIdx.x * 4 + (threadIdx.x >> 6);
  const int lane = threadIdx.x & 63;
  if (row >= M_) return;
  const float* r = ho + (size_t)row * HOUT;
  float v1 = (lane < NCLS) ? r[lane] : -3.0e38f;
  float v2 = (lane + 64 < NCLS) ? r[lane + 64] : -3.0e38f;
  float mx = fmaxf(v1, v2);
#pragma unroll
  for (int off = 32; off; off >>= 1) mx = fmaxf(mx, __shfl_xor(mx, off));
  float s = ((lane < NCLS) ? expf(v1 - mx) : 0.0f) + ((lane + 64 < NCLS) ? expf(v2 - mx) : 0.0f);
#pragma unroll
  for (int off = 32; off; off >>= 1) s += __shfl_xor(s, off);
  if (lane == 0) { mxv[row] = mx; invv[row] = 1.0f / s; }
}

// ---------------- decode + NMS prep: one thread per (roi, class) ----------------
__global__ __launch_bounds__(256) void decode_kernel(const float* __restrict__ ho,
                                                     const float* __restrict__ mxv,
                                                     const float* __restrict__ invv,
                                                     const float* __restrict__ props,
                                                     float* __restrict__ boxes,
                                                     float* __restrict__ scores,
                                                     float* __restrict__ swork,
                                                     float* __restrict__ boff,
                                                     float* __restrict__ area) {
  const int idx = blockIdx.x * 256 + threadIdx.x;
  if (idx >= M_ * 90) return;
  const int n = idx / 90;
  const int k = idx - n * 90 + 1;
  const float* row = ho + (size_t)n * HOUT;
  const float sc = expf(row[k] - mxv[n]) * invv[n];
  const float* p = props + n * 4;
  const float px1 = p[0], py1 = p[1], px2 = p[2], py2 = p[3];
  const float pw = px2 - px1, ph = py2 - py1;
  const float pcx = px1 + 0.5f * pw, pcy = py1 + 0.5f * ph;
  const float* d = row + NCLS + 4 * k;
  const float dx = d[0] * 0.1f;
  const float dy = d[1] * 0.1f;
  const float dw = fminf(d[2] * 0.2f, BBOX_CLIPF);
  const float dh = fminf(d[3] * 0.2f, BBOX_CLIPF);
  const float cx = dx * pw + pcx, cy = dy * ph + pcy;
  const float w = pw * expf(dw), h = ph * expf(dh);
  const float bx1 = fminf(fmaxf(cx - 0.5f * w, 0.0f), IMGF);
  const float by1 = fminf(fmaxf(cy - 0.5f * h, 0.0f), IMGF);
  const float bx2 = fminf(fmaxf(cx + 0.5f * w, 0.0f), IMGF);
  const float by2 = fminf(fmaxf(cy + 0.5f * h, 0.0f), IMGF);
  const int j = idx;
  boxes[4 * j + 0] = bx1; boxes[4 * j + 1] = by1;
  boxes[4 * j + 2] = bx2; boxes[4 * j + 3] = by2;
  scores[j] = sc;
  const float wv = bx2 - bx1, hv = by2 - by1;
  swork[j] = ((sc > 0.05f) && (wv >= 1.0f) && (hv >= 1.0f)) ? sc : NEGV;
  const float off = (float)k * (IMGF + 2.0f);
  const float ox1 = bx1 + off, oy1 = by1 + off, ox2 = bx2 + off, oy2 = by2 + off;
  boff[4 * j + 0] = ox1; boff[4 * j + 1] = oy1;
  boff[4 * j + 2] = ox2; boff[4 * j + 3] = oy2;
  area[j] = (ox2 - ox1) * (oy2 - oy1);
}

// ---------------- NMS: replicates jax.lax.scan semantics exactly ----------------
__global__ __launch_bounds__(1024) void nms_kernel(const float* __restrict__ boxes,
                                                   const float* __restrict__ scores,
                                                   float* __restrict__ swork,
                                                   const float* __restrict__ boff,
                                                   const float* __restrict__ area,
                                                   float* __restrict__ dout) {
  const int b = blockIdx.x;
  const int t = threadIdx.x;
  const float* Bx = boxes + (size_t)b * NMSM * 4;
  const float* Sc = scores + (size_t)b * NMSM;
  float* Sw = swork + (size_t)b * NMSM;
  const float* Bo = boff + (size_t)b * NMSM * 4;
  const float* Ar = area + (size_t)b * NMSM;
  float* dets = dout + b * (DET_ * 5);
  float* labels = dout + B_ * DET_ * 5 + b * DET_;
  __shared__ float s_val[1024];
  __shared__ int s_idx[1024];
  __shared__ float s_box[4];
  __shared__ float s_area;
  __shared__ int s_ok;
  for (int it = 0; it < DET_; ++it) {
    float bv = -3.0e38f;
    int bi = 0;
    for (int j = t; j < NMSM; j += 1024) {
      float v = Sw[j];
      if (v > bv) { bv = v; bi = j; }
    }
    s_val[t] = bv;
    s_idx[t] = bi;
    __syncthreads();
    for (int off = 512; off > 0; off >>= 1) {
      if (t < off) {
        float v2 = s_val[t + off]; int i2 = s_idx[t + off];
        if (v2 > s_val[t] || (v2 == s_val[t] && i2 < s_idx[t])) { s_val[t] = v2; s_idx[t] = i2; }
      }
      __syncthreads();
    }
    if (t == 0) {
      int i = s_idx[0];
      int ok = (s_val[0] > NEGV * 0.5f) ? 1 : 0;
      s_ok = ok;
      if (ok) {
        dets[it * 5 + 0] = Bx[i * 4 + 0];
        dets[it * 5 + 1] = Bx[i * 4 + 1];
        dets[it * 5 + 2] = Bx[i * 4 + 2];
        dets[it * 5 + 3] = Bx[i * 4 + 3];
        dets[it * 5 + 4] = Sc[i];
        labels[it] = (float)(i % 90 + 1);
        s_box[0] = Bo[i * 4 + 0]; s_box[1] = Bo[i * 4 + 1];
        s_box[2] = Bo[i * 4 + 2]; s_box[3] = Bo[i * 4 + 3];
        s_area = Ar[i];
        Sw[i] = NEGV;
      }
    }
    __syncthreads();
    if (!s_ok) {
      for (int tt = it + t; tt < DET_; tt += 1024) {
        dets[tt * 5 + 0] = 0.0f; dets[tt * 5 + 1] = 0.0f; dets[tt * 5 + 2] = 0.0f;
        dets[tt * 5 + 3] = 0.0f; dets[tt * 5 + 4] = 0.0f;
        labels[tt] = -1.0f;
      }
      return;
    }
    const float bx1 = s_box[0], by1 = s_box[1], bx2 = s_box[2], by2 = s_box[3], ai = s_area;
    for (int j = t; j < NMSM; j += 1024) {
      float v = Sw[j];
      if (v <= NEGV * 0.5f) continue;
      float ix1 = fmaxf(bx1, Bo[j * 4 + 0]);
      float iy1 = fmaxf(by1, Bo[j * 4 + 1]);
      float ix2 = fminf(bx2, Bo[j * 4 + 2]);
      float iy2 = fminf(by2, Bo[j * 4 + 3]);
      float inter = fmaxf(ix2 - ix1, 0.0f) * fmaxf(iy2 - iy1, 0.0f);
      float iou = inter / (ai + Ar[j] - inter + 1e-9f);
      if (iou > 0.5f) Sw[j] = NEGV;
    }
    __syncthreads();
  }
}

// ---------------- launch ----------------
extern "C" void kernel_launch(void* const* d_in, const int* in_sizes, int n_in,
                              void* d_out, int out_size, void* d_ws, size_t ws_size,
                              hipStream_t stream) {
  const float* features  = (const float*)d_in[0];
  const float* proposals = (const float*)d_in[1];
  const float* w1   = (const float*)d_in[2];
  const float* b1   = (const float*)d_in[3];
  const float* w2   = (const float*)d_in[4];
  const float* b2   = (const float*)d_in[5];
  const float* wcls = (const float*)d_in[6];
  const float* bcls = (const float*)d_in[7];
  const float* wbb  = (const float*)d_in[8];
  const float* bbb  = (const float*)d_in[9];
  (void)in_sizes; (void)n_in; (void)out_size;

  char* p = (char*)d_ws;
  auto alloc = [&](size_t bytes) {
    char* r = p;
    p += (bytes + 255) & ~(size_t)255;
    return r;
  };
  bf16_t* A      = (bf16_t*)alloc((size_t)MPAD * DIN * 2);
  bf16_t* w1t    = (bf16_t*)alloc((size_t)REP_ * DIN * 2);
  bf16_t* w2t    = (bf16_t*)alloc((size_t)REP_ * REP_ * 2);
  bf16_t* wht    = (bf16_t*)alloc((size_t)HOUT * REP_ * 2);
  float*  biash  = (float*)alloc((size_t)HOUT * 4);
  bf16_t* h1     = (bf16_t*)alloc((size_t)MPAD * REP_ * 2);
  bf16_t* h2     = (bf16_t*)alloc((size_t)MPAD * REP_ * 2);
  float*  ho     = (float*)alloc((size_t)MPAD * HOUT * 4);
  float*  mxv    = (float*)alloc((size_t)M_ * 4);
  float*  invv   = (float*)alloc((size_t)M_ * 4);
  float*  boxes  = (float*)alloc((size_t)B_ * NMSM * 4 * 4);
  float*  scoresb= (float*)alloc((size_t)B_ * NMSM * 4);
  float*  sworkb = (float*)alloc((size_t)B_ * NMSM * 4);
  float*  boffb  = (float*)alloc((size_t)B_ * NMSM * 4 * 4);
  float*  areab  = (float*)alloc((size_t)B_ * NMSM * 4);

  size_t used = (size_t)(p - (char*)d_ws);
  size_t avail = (ws_size > used) ? (ws_size - used) : 0;
  bf16_t* partialH = (bf16_t*)p;   // bf16 partials (FC1/FC2)
  float*  partialF = (float*)p;    // f32 partials (FC3, stream-ordered reuse)
  const size_t chunkH = (size_t)MPAD * REP_ * 2;   // 4 MB
  const size_t chunkF = (size_t)MPAD * HOUT * 4;   // 4 MB
  int KC1 = 8;   // kLen = 1568, G = 49
  while (KC1 > 1 && (size_t)KC1 * chunkH > avail) KC1 >>= 1;
  int KC2 = 2;   // kLen = 512, G = 16; 256 blocks
  while (KC2 > 1 && (size_t)KC2 * chunkH > avail) KC2 >>= 1;
  int KC3 = 4;   // kLen = 256, G = 8; 256 blocks
  while (KC3 > 1 && (size_t)KC3 * chunkF > avail) KC3 >>= 1;

  // fused pre: roi + weight transposes + head concat in one launch
  fused_pre_kernel<<<NROIB + NW1B + NW2B + NHWB + 1, 256, 0, stream>>>(
      features, proposals, w1, w2, wcls, wbb, bcls, bbb, A, w1t, w2t, wht, biash);

  // FC1: [2048 x 12544] @ [12544 x 1024] -> h1 (relu, bf16). 8-wave depth-3 pipeline.
  gemm8_kernel<<<32 * KC1, 512, 0, stream>>>(A, w1t, partialH, DIN, DIN / KC1, KC1);
  reduceH_kernel<<<(MPAD * REP_ / 8) / 256, 256, 0, stream>>>(partialH, b1, h1, KC1);
  // FC2: [2048 x 1024] @ [1024 x 1024] -> h2 (relu, bf16). 4-wave 128-tile pipeline, KC=2.
  gemm128_kernel<bf16_t><<<(MPAD / 128) * (REP_ / 128) * KC2, 256, 0, stream>>>(
      h1, w2t, partialH, REP_, REP_ / KC2, KC2, REP_ / 128, REP_);
  reduceH_kernel<<<(MPAD * REP_ / 8) / 256, 256, 0, stream>>>(partialH, b2, h2, KC2);
  // FC3 (heads): [2048 x 1024] @ [1024 x 512] -> ho (f32). 4-wave 128-tile pipeline, KC=4.
  gemm128_kernel<float><<<(MPAD / 128) * (HOUT / 128) * KC3, 256, 0, stream>>>(
      h2, wht, partialF, REP_, REP_ / KC3, KC3, HOUT / 128, HOUT);
  reduce_kernel<<<(MPAD * HOUT / 4) / 256, 256, 0, stream>>>(partialF, biash, ho, HOUT, KC3);

  rowsm_kernel<<<(M_ + 3) / 4, 256, 0, stream>>>(ho, mxv, invv);
  decode_kernel<<<(M_ * 90 + 255) / 256, 256, 0, stream>>>(ho, mxv, invv, proposals,
                                                           boxes, scoresb, sworkb, boffb, areab);
  nms_kernel<<<B_, 1024, 0, stream>>>(boxes, scoresb, sworkb, boffb, areab, (float*)d_out);
}

// Round 16
// 164.158 us; speedup vs baseline: 1.2889x; 1.0715x over previous
//
#include <hip/hip_runtime.h>
#include <stdint.h>

// ---------------- problem constants (hard-coded from reference) ----------------
#define B_    2
#define N_    1000
#define C_    256
#define H_    50
#define W_    50
#define P_    7
#define NCLS  91
#define REP_  1024
#define DIN   (C_ * P_ * P_)   // 12544
#define M_    (B_ * N_)        // 2000
#define MPAD  2048
#define HOUT  512              // padded head cols (91 cls + 364 bbox = 455 real)
#define DET_  100
#define NMSM  (N_ * 90)        // 90000 candidates per batch
#define NEGV  (-1000000000.0f)
#define SCALE_ 0.0625f
#define IMGF  800.0f
#define BBOX_CLIPF 4.135166556742356f  // log(1000/16)

#define NPIX  (H_ * W_)        // 2500
#define NW1B  ((DIN / 32) * (REP_ / 32))    // 12544
#define NW2B  ((REP_ / 32) * (REP_ / 32))   // 1024
#define NHWB  ((HOUT * REP_) / 256)         // 2048

typedef __bf16 bf16_t;
typedef __attribute__((ext_vector_type(8))) __bf16 bf16x8;
typedef __attribute__((ext_vector_type(4))) __bf16 bf16x4;
typedef __attribute__((ext_vector_type(4))) float f32x4;
typedef __attribute__((ext_vector_type(4))) int i32x4;

// async global->LDS, 16B per lane. LDS dest must be wave-uniform base (+lane*16 by HW).
__device__ __forceinline__ void gload16(const void* g, void* l) {
  auto gp = (const __attribute__((address_space(1))) uint32_t*)(uintptr_t)g;
  auto lp = (__attribute__((address_space(3))) uint32_t*)(uint32_t)(uintptr_t)l;
  __builtin_amdgcn_global_load_lds(gp, lp, 16, 0, 0);
}

// ---------------- features -> channels-last copy: ft[b][p][c] = features[b][c][p] ----------------
__global__ __launch_bounds__(256) void ft_kernel(const float* __restrict__ features,
                                                 float* __restrict__ ft) {
  __shared__ float tile[32][33];
  const int pb = blockIdx.x;            // p-tile (79 tiles of 32, last partial)
  const int cb = blockIdx.y;            // c-tile (8 tiles of 32)
  const int b  = blockIdx.z;
  const int p0 = pb * 32, c0 = cb * 32;
  const int tx = threadIdx.x & 31;
  const int ty = threadIdx.x >> 5;      // 0..7
  const float* in = features + (size_t)b * C_ * NPIX;
#pragma unroll
  for (int j = 0; j < 4; ++j) {
    int c = c0 + ty + j * 8;
    int p = p0 + tx;
    tile[ty + j * 8][tx] = (p < NPIX) ? in[(size_t)c * NPIX + p] : 0.0f;
  }
  __syncthreads();
  float* out = ft + (size_t)b * NPIX * C_;
#pragma unroll
  for (int j = 0; j < 4; ++j) {
    int p = p0 + ty + j * 8;
    int c = c0 + tx;
    if (p < NPIX) out[(size_t)p * C_ + c] = tile[tx][ty + j * 8];
  }
}

// ---------------- fused pre: ROI align (channels-last) + w^T transposes + head concat --------
// Disjoint blockIdx ranges; 26.7KB LDS carve.
// roi: block = one roi; coalesced f32x4 corner reads from ft; out staged in LDS [c][pp].
__global__ __launch_bounds__(256) void fused_pre_kernel(const float* __restrict__ ft,
                                                        const float* __restrict__ proposals,
                                                        const float* __restrict__ w1,
                                                        const float* __restrict__ w2,
                                                        const float* __restrict__ wcls,
                                                        const float* __restrict__ wbb,
                                                        const float* __restrict__ bcls,
                                                        const float* __restrict__ bbb,
                                                        bf16_t* __restrict__ A,
                                                        bf16_t* __restrict__ w1t,
                                                        bf16_t* __restrict__ w2t,
                                                        bf16_t* __restrict__ wht,
                                                        float* __restrict__ biash) {
  __shared__ __align__(16) char smem[26656];
  int bidx = blockIdx.x;
  const int t = threadIdx.x;

  if (bidx < MPAD) {
    // ---------------- ROI align branch (one block per roi row) ----------------
    const int n = bidx;
    if (n >= M_) {
      f32x4 z = {0.f, 0.f, 0.f, 0.f};
      f32x4* arow = (f32x4*)(A + (size_t)n * DIN);   // 1568 x 16B
      for (int i = t; i < DIN / 8; i += 256) arow[i] = z;
      return;
    }
    int*   s_o = (int*)smem;                    // [49][4]  784 B
    float* s_w = (float*)(smem + 784);          // [49][4]  784 B
    bf16_t* sOut = (bf16_t*)(smem + 1568);      // [256][49] = 25088 B
    if (t < 49) {
      const int py = t / 7, px = t - (t / 7) * 7;
      const float* p = proposals + n * 4;
      float y1 = p[1] * SCALE_, y2 = p[3] * SCALE_;
      float bh = (y2 - y1) * (1.0f / 7.0f);
      float y = y1 + ((float)py + 0.5f) * bh - 0.5f;
      y = fminf(fmaxf(y, 0.0f), 49.0f);
      int y0 = (int)floorf(y);
      int dy = (y0 < 49) ? 1 : 0;
      float ly = y - (float)y0;
      float x1 = p[0] * SCALE_, x2 = p[2] * SCALE_;
      float bw = (x2 - x1) * (1.0f / 7.0f);
      float x = x1 + ((float)px + 0.5f) * bw - 0.5f;
      x = fminf(fmaxf(x, 0.0f), 49.0f);
      int x0 = (int)floorf(x);
      int dx = (x0 < 49) ? 1 : 0;
      float lx = x - (float)x0;
      const float hy = 1.0f - ly, hx = 1.0f - lx;
      int o00 = (y0 * W_ + x0) * C_;            // float offset into ft plane
      s_o[t * 4 + 0] = o00;
      s_o[t * 4 + 1] = o00 + dx * C_;
      s_o[t * 4 + 2] = o00 + dy * (W_ * C_);
      s_o[t * 4 + 3] = o00 + dy * (W_ * C_) + dx * C_;
      s_w[t * 4 + 0] = hy * hx;
      s_w[t * 4 + 1] = hy * lx;
      s_w[t * 4 + 2] = ly * hx;
      s_w[t * 4 + 3] = ly * lx;
    }
    __syncthreads();
    const int b = (n >= N_) ? 1 : 0;
    const float* fb = ft + (size_t)b * NPIX * C_;
    const int wv = t >> 6, l = t & 63;
    const int c4 = l * 4;
    for (int pp = wv; pp < 49; pp += 4) {
      const i32x4 o = *(const i32x4*)&s_o[pp * 4];
      const f32x4 wq = *(const f32x4*)&s_w[pp * 4];
      const f32x4 a00 = *(const f32x4*)(fb + o[0] + c4);
      const f32x4 a01 = *(const f32x4*)(fb + o[1] + c4);
      const f32x4 a10 = *(const f32x4*)(fb + o[2] + c4);
      const f32x4 a11 = *(const f32x4*)(fb + o[3] + c4);
      const f32x4 v = a00 * wq[0] + a01 * wq[1] + a10 * wq[2] + a11 * wq[3];
#pragma unroll
      for (int i = 0; i < 4; ++i) sOut[(c4 + i) * 49 + pp] = (bf16_t)v[i];
    }
    __syncthreads();
    // A row write: LDS [c][pp] is exactly the A-row k-order (k = c*49+pp)
    f32x4* arow = (f32x4*)(A + (size_t)n * DIN);
    const f32x4* so = (const f32x4*)sOut;
    for (int i = t; i < DIN / 8; i += 256) arow[i] = so[i];
    return;
  }
  bidx -= MPAD;

  if (bidx < NW1B + NW2B) {
    // ---------------- transpose+convert branch: f32 [K][N] -> bf16 [N][K] ----------------
    float* tile = (float*)smem;  // [32][33]
    const float* in;
    bf16_t* out;
    int K, N, kbk, nbk;
    if (bidx < NW1B) {
      in = w1; out = w1t; K = DIN; N = REP_;
      kbk = bidx % (DIN / 32); nbk = bidx / (DIN / 32);
    } else {
      bidx -= NW1B;
      in = w2; out = w2t; K = REP_; N = REP_;
      kbk = bidx % (REP_ / 32); nbk = bidx / (REP_ / 32);
    }
    const int k0 = kbk * 32, n0 = nbk * 32;
    const int tx = t & 31;
    const int ty = t >> 5;
#pragma unroll
    for (int j = 0; j < 4; ++j) {
      int ky = ty + j * 8;
      tile[ky * 33 + tx] = in[(size_t)(k0 + ky) * N + n0 + tx];
    }
    __syncthreads();
    const int qx = t & 7;
    const int ny = t >> 3;
    bf16x4 o;
#pragma unroll
    for (int i = 0; i < 4; ++i) o[i] = (bf16_t)tile[(4 * qx + i) * 33 + ny];
    *(bf16x4*)(&out[(size_t)(n0 + ny) * K + k0 + 4 * qx]) = o;
  } else if (bidx < NW1B + NW2B + NHWB) {
    // ---------------- head weight concat ----------------
    int idx = (bidx - NW1B - NW2B) * 256 + t;
    int j = idx >> 10;
    int k = idx & 1023;
    float v = 0.0f;
    if (j < NCLS) v = wcls[(size_t)k * NCLS + j];
    else if (j < 455) v = wbb[(size_t)k * 364 + (j - NCLS)];
    wht[idx] = (bf16_t)v;
  } else {
    // ---------------- head bias ----------------
    for (int j = t; j < HOUT; j += 256) {
      float v = 0.0f;
      if (j < NCLS) v = bcls[j];
      else if (j < 455) v = bbb[j - NCLS];
      biash[j] = v;
    }
  }
}

// ---------------- FC1: 256x256-tile deep-pipelined MFMA GEMM (8-wave, split-K) ----------------
// [R9-proven: 57us] 4 LDS buffers (128 KiB), depth-3 prefetch, one-shot frag reads,
// single barrier/K-tile, st_16x32 swizzle both-sides, zc = bid % KC XCD pinning.
__global__ __launch_bounds__(512, 2) void gemm8_kernel(const bf16_t* __restrict__ A,
                                                       const bf16_t* __restrict__ Bt,
                                                       bf16_t* __restrict__ partial,
                                                       int K, int kLen, int KC) {
  __shared__ __align__(16) bf16_t lds[4 * 2 * 2 * 128 * 32];  // 128 KiB
  const int t = threadIdx.x;
  const int lane = t & 63;
  const int w = t >> 6;         // 0..7
  const int wm = w >> 2;        // 0..1
  const int wn = w & 3;         // 0..3
  const int bid = blockIdx.x;
  const int zc = bid % KC;
  const int inner = bid / KC;   // 0..31
  const int row0 = (inner >> 2) * 256;
  const int col0 = (inner & 3) * 256;
  const int kOff = zc * kLen;
  const int G = kLen >> 5;

  const int lr = lane & 15;
  const int kb = (lane >> 4) * 16;
  int aoff[8], boff[4];
#pragma unroll
  for (int m = 0; m < 8; ++m) {
    int r = m * 16 + lr;
    aoff[m] = (r * 64 + kb) ^ (((r >> 3) & 1) << 5);
  }
#pragma unroll
  for (int n = 0; n < 4; ++n) {
    int r = (wn & 1) * 64 + n * 16 + lr;
    boff[n] = (r * 64 + kb) ^ (((r >> 3) & 1) << 5);
  }

  const int s_row = t >> 2;
  const int s_k8 = (t & 3) ^ (((s_row >> 3) & 1) << 1);
  const bf16_t* pAs = A + (size_t)(row0 + s_row) * K + kOff + s_k8 * 8;
  const bf16_t* pBs = Bt + (size_t)(col0 + s_row) * K + kOff + s_k8 * 8;
  const size_t halfStride = (size_t)128 * K;
  char* ldsBase = (char*)&lds[0];
  const int wOff = w << 10;

  auto stage = [&](int buf, int hp, int kt) {
    const bf16_t* src = ((hp < 2) ? pAs : pBs) + (size_t)(hp & 1) * halfStride + kt * 32;
    char* dst = ldsBase + buf * 32768 + (hp >> 1) * 16384 + (hp & 1) * 8192 + wOff;
    gload16(src, dst);
  };

  f32x4 acc[8][4] = {};

#pragma unroll
  for (int hp = 0; hp < 4; ++hp) stage(0, hp, 0);
#pragma unroll
  for (int hp = 0; hp < 4; ++hp) stage(1, hp, 1);
#pragma unroll
  for (int hp = 0; hp < 4; ++hp) stage(2, hp, 2);
  asm volatile("s_waitcnt vmcnt(8)" ::: "memory");
  __builtin_amdgcn_s_barrier();
  __builtin_amdgcn_sched_barrier(0);

  for (int g = 0; g < G; ++g) {
    const int cb = g & 3;
    const int sb = (g + 3) & 3;
    const bool doStage = (g + 3) < G;
    if (doStage) {
#pragma unroll
      for (int hp = 0; hp < 4; ++hp) stage(sb, hp, g + 3);
    }
    char* lA = ldsBase + cb * 32768 + wm * 8192;
    char* lB = ldsBase + cb * 32768 + 16384 + (wn >> 1) * 8192;
    bf16x8 af[8], bfv[4];
#pragma unroll
    for (int i = 0; i < 8; ++i) af[i] = *(const bf16x8*)(lA + aoff[i]);
#pragma unroll
    for (int j2 = 0; j2 < 4; ++j2) bfv[j2] = *(const bf16x8*)(lB + boff[j2]);
    asm volatile("s_waitcnt lgkmcnt(0)" ::: "memory");
    if (doStage)          asm volatile("s_waitcnt vmcnt(8)" ::: "memory");
    else if (g == G - 3)  asm volatile("s_waitcnt vmcnt(4)" ::: "memory");
    else                  asm volatile("s_waitcnt vmcnt(0)" ::: "memory");
    __builtin_amdgcn_sched_barrier(0);
    __builtin_amdgcn_s_barrier();
    __builtin_amdgcn_sched_barrier(0);
    __builtin_amdgcn_s_setprio(1);
#pragma unroll
    for (int i = 0; i < 8; ++i)
#pragma unroll
      for (int j2 = 0; j2 < 4; ++j2)
        acc[i][j2] = __builtin_amdgcn_mfma_f32_16x16x32_bf16(af[i], bfv[j2], acc[i][j2], 0, 0, 0);
    __builtin_amdgcn_s_setprio(0);
    __builtin_amdgcn_sched_barrier(0);
  }

  bf16_t* out = partial + (size_t)zc * MPAD * REP_;
  const int crow = (lane >> 4) * 4;
#pragma unroll
  for (int n = 0; n < 4; ++n) {
    const int col = col0 + wn * 64 + n * 16 + lr;
#pragma unroll
    for (int m = 0; m < 8; ++m) {
      const int rowb = row0 + wm * 128 + m * 16 + crow;
#pragma unroll
      for (int j2 = 0; j2 < 4; ++j2)
        out[(size_t)(rowb + j2) * REP_ + col] = (bf16_t)acc[m][n][j2];
    }
  }
}

// ---------------- FC2/FC3: 128x128-tile deep-pipelined GEMM (4-wave, split-K) ----------------
// [R14-proven] Geometry port of gemm8's schedule; 64KB LDS (2 blocks/CU); same swizzle.
template <typename OT>
__global__ __launch_bounds__(256, 2) void gemm128_kernel(const bf16_t* __restrict__ A,
                                                         const bf16_t* __restrict__ Bt,
                                                         OT* __restrict__ partial,
                                                         int K, int kLen, int KC,
                                                         int GN, int ldc) {
  __shared__ __align__(16) bf16_t lds[4 * 2 * 128 * 32];  // 64 KiB
  const int t = threadIdx.x;
  const int lane = t & 63;
  const int w = t >> 6;         // 0..3
  const int wm = w >> 1;        // 0..1
  const int wn = w & 1;         // 0..1
  const int bid = blockIdx.x;
  const int zc = bid % KC;
  const int inner = bid / KC;
  const int row0 = (inner / GN) * 128;
  const int col0 = (inner % GN) * 128;
  const int kOff = zc * kLen;
  const int G = kLen >> 5;      // >= 3

  const int lr = lane & 15;
  const int kb = (lane >> 4) * 16;
  int aoff[4], boff[4];
#pragma unroll
  for (int m = 0; m < 4; ++m) {
    int r = wm * 64 + m * 16 + lr;
    aoff[m] = (r * 64 + kb) ^ (((r >> 3) & 1) << 5);
  }
#pragma unroll
  for (int n = 0; n < 4; ++n) {
    int r = wn * 64 + n * 16 + lr;
    boff[n] = (r * 64 + kb) ^ (((r >> 3) & 1) << 5);
  }

  const int s_row = t >> 2;                                // 0..63
  const int s_k8 = (t & 3) ^ (((s_row >> 3) & 1) << 1);    // bit3 invariant under +64
  const bf16_t* pAs = A + (size_t)(row0 + s_row) * K + kOff + s_k8 * 8;
  const bf16_t* pBs = Bt + (size_t)(col0 + s_row) * K + kOff + s_k8 * 8;
  const size_t halfStride = (size_t)64 * K;
  char* ldsBase = (char*)&lds[0];
  const int wOff = w << 10;

  auto stage = [&](int buf, int hp, int kt) {
    const bf16_t* src = ((hp < 2) ? pAs : pBs) + (size_t)(hp & 1) * halfStride + kt * 32;
    char* dst = ldsBase + buf * 16384 + (hp >> 1) * 8192 + (hp & 1) * 4096 + wOff;
    gload16(src, dst);
  };

  f32x4 acc[4][4] = {};

#pragma unroll
  for (int hp = 0; hp < 4; ++hp) stage(0, hp, 0);
#pragma unroll
  for (int hp = 0; hp < 4; ++hp) stage(1, hp, 1);
#pragma unroll
  for (int hp = 0; hp < 4; ++hp) stage(2, hp, 2);
  asm volatile("s_waitcnt vmcnt(8)" ::: "memory");
  __builtin_amdgcn_s_barrier();
  __builtin_amdgcn_sched_barrier(0);

  for (int g = 0; g < G; ++g) {
    const int cb = g & 3;
    const int sb = (g + 3) & 3;
    const bool doStage = (g + 3) < G;
    if (doStage) {
#pragma unroll
      for (int hp = 0; hp < 4; ++hp) stage(sb, hp, g + 3);
    }
    char* lA = ldsBase + cb * 16384;
    char* lB = ldsBase + cb * 16384 + 8192;
    bf16x8 af[4], bfv[4];
#pragma unroll
    for (int i = 0; i < 4; ++i) af[i] = *(const bf16x8*)(lA + aoff[i]);
#pragma unroll
    for (int j2 = 0; j2 < 4; ++j2) bfv[j2] = *(const bf16x8*)(lB + boff[j2]);
    asm volatile("s_waitcnt lgkmcnt(0)" ::: "memory");
    if (doStage)          asm volatile("s_waitcnt vmcnt(8)" ::: "memory");
    else if (g == G - 3)  asm volatile("s_waitcnt vmcnt(4)" ::: "memory");
    else                  asm volatile("s_waitcnt vmcnt(0)" ::: "memory");
    __builtin_amdgcn_sched_barrier(0);
    __builtin_amdgcn_s_barrier();
    __builtin_amdgcn_sched_barrier(0);
    __builtin_amdgcn_s_setprio(1);
#pragma unroll
    for (int i = 0; i < 4; ++i)
#pragma unroll
      for (int j2 = 0; j2 < 4; ++j2)
        acc[i][j2] = __builtin_amdgcn_mfma_f32_16x16x32_bf16(af[i], bfv[j2], acc[i][j2], 0, 0, 0);
    __builtin_amdgcn_s_setprio(0);
    __builtin_amdgcn_sched_barrier(0);
  }

  OT* out = partial + (size_t)zc * MPAD * ldc;
  const int crow = (lane >> 4) * 4;
#pragma unroll
  for (int n = 0; n < 4; ++n) {
    const int col = col0 + wn * 64 + n * 16 + lr;
#pragma unroll
    for (int m = 0; m < 4; ++m) {
      const int rowb = row0 + wm * 64 + m * 16 + crow;
#pragma unroll
      for (int j2 = 0; j2 < 4; ++j2)
        out[(size_t)(rowb + j2) * ldc + col] = (OT)acc[m][n][j2];
    }
  }
}

// ---------------- bf16 split-K reduce: out = relu(sum + bias) -> bf16 (8/thread, ldc=REP_) ----
__global__ __launch_bounds__(256) void reduceH_kernel(const bf16_t* __restrict__ partial,
                                                      const float* __restrict__ bias,
                                                      bf16_t* __restrict__ out,
                                                      int KC) {
  const size_t idx8 = ((size_t)blockIdx.x * 256 + threadIdx.x) * 8;
  const size_t stride = (size_t)MPAD * REP_;
  float s[8] = {};
  for (int c = 0; c < KC; ++c) {
    const bf16x8 v = *(const bf16x8*)(partial + c * stride + idx8);
#pragma unroll
    for (int j = 0; j < 8; ++j) s[j] += (float)v[j];
  }
  const int col = (int)(idx8 & (size_t)(REP_ - 1));
  const f32x4 b0 = *(const f32x4*)(bias + col);
  const f32x4 b1 = *(const f32x4*)(bias + col + 4);
  bf16x8 o;
#pragma unroll
  for (int j = 0; j < 4; ++j) o[j] = (bf16_t)fmaxf(s[j] + b0[j], 0.0f);
#pragma unroll
  for (int j = 0; j < 4; ++j) o[4 + j] = (bf16_t)fmaxf(s[4 + j] + b1[j], 0.0f);
  *(bf16x8*)(out + idx8) = o;
}

// ---------------- f32 split-K reduce: out = sum + bias (f32) ----------------
__global__ __launch_bounds__(256) void reduce_kernel(const float* __restrict__ partial,
                                                     const float* __restrict__ bias,
                                                     float* __restrict__ out,
                                                     int ldc, int KC) {
  const size_t idx4 = ((size_t)blockIdx.x * 256 + threadIdx.x) * 4;
  f32x4 s = *(const f32x4*)(partial + idx4);
  const size_t stride = (size_t)MPAD * ldc;
  for (int c = 1; c < KC; ++c) s += *(const f32x4*)(partial + c * stride + idx4);
  const int col = (int)(idx4 & (size_t)(ldc - 1));
  s += *(const f32x4*)(bias + col);
  *(f32x4*)(out + idx4) = s;
}

// ---------------- row softmax stats: one wave per row ----------------
__global__ __launch_bounds__(256) void rowsm_kernel(const float* __restrict__ ho,
                                                    float* __restrict__ mxv,
                                                    float* __restrict__ invv) {
  const int row = blockIdx.x * 4 + (threadIdx.x >> 6);
  const int lane = threadIdx.x & 63;
  if (row >= M_) return;
  const float* r = ho + (size_t)row * HOUT;
  float v1 = (lane < NCLS) ? r[lane] : -3.0e38f;
  float v2 = (lane + 64 < NCLS) ? r[lane + 64] : -3.0e38f;
  float mx = fmaxf(v1, v2);
#pragma unroll
  for (int off = 32; off; off >>= 1) mx = fmaxf(mx, __shfl_xor(mx, off));
  float s = ((lane < NCLS) ? expf(v1 - mx) : 0.0f) + ((lane + 64 < NCLS) ? expf(v2 - mx) : 0.0f);
#pragma unroll
  for (int off = 32; off; off >>= 1) s += __shfl_xor(s, off);
  if (lane == 0) { mxv[row] = mx; invv[row] = 1.0f / s; }
}

// ---------------- decode + NMS prep: one thread per (roi, class) ----------------
__global__ __launch_bounds__(256) void decode_kernel(const float* __restrict__ ho,
                                                     const float* __restrict__ mxv,
                                                     const float* __restrict__ invv,
                                                     const float* __restrict__ props,
                                                     float* __restrict__ boxes,
                                                     float* __restrict__ scores,
                                                     float* __restrict__ swork,
                                                     float* __restrict__ boff,
                                                     float* __restrict__ area) {
  const int idx = blockIdx.x * 256 + threadIdx.x;
  if (idx >= M_ * 90) return;
  const int n = idx / 90;
  const int k = idx - n * 90 + 1;
  const float* row = ho + (size_t)n * HOUT;
  const float sc = expf(row[k] - mxv[n]) * invv[n];
  const float* p = props + n * 4;
  const float px1 = p[0], py1 = p[1], px2 = p[2], py2 = p[3];
  const float pw = px2 - px1, ph = py2 - py1;
  const float pcx = px1 + 0.5f * pw, pcy = py1 + 0.5f * ph;
  const float* d = row + NCLS + 4 * k;
  const float dx = d[0] * 0.1f;
  const float dy = d[1] * 0.1f;
  const float dw = fminf(d[2] * 0.2f, BBOX_CLIPF);
  const float dh = fminf(d[3] * 0.2f, BBOX_CLIPF);
  const float cx = dx * pw + pcx, cy = dy * ph + pcy;
  const float w = pw * expf(dw), h = ph * expf(dh);
  const float bx1 = fminf(fmaxf(cx - 0.5f * w, 0.0f), IMGF);
  const float by1 = fminf(fmaxf(cy - 0.5f * h, 0.0f), IMGF);
  const float bx2 = fminf(fmaxf(cx + 0.5f * w, 0.0f), IMGF);
  const float by2 = fminf(fmaxf(cy + 0.5f * h, 0.0f), IMGF);
  const int j = idx;
  boxes[4 * j + 0] = bx1; boxes[4 * j + 1] = by1;
  boxes[4 * j + 2] = bx2; boxes[4 * j + 3] = by2;
  scores[j] = sc;
  const float wv = bx2 - bx1, hv = by2 - by1;
  swork[j] = ((sc > 0.05f) && (wv >= 1.0f) && (hv >= 1.0f)) ? sc : NEGV;
  const float off = (float)k * (IMGF + 2.0f);
  const float ox1 = bx1 + off, oy1 = by1 + off, ox2 = bx2 + off, oy2 = by2 + off;
  boff[4 * j + 0] = ox1; boff[4 * j + 1] = oy1;
  boff[4 * j + 2] = ox2; boff[4 * j + 3] = oy2;
  area[j] = (ox2 - ox1) * (oy2 - oy1);
}

// ---------------- NMS: replicates jax.lax.scan semantics exactly ----------------
__global__ __launch_bounds__(1024) void nms_kernel(const float* __restrict__ boxes,
                                                   const float* __restrict__ scores,
                                                   float* __restrict__ swork,
                                                   const float* __restrict__ boff,
                                                   const float* __restrict__ area,
                                                   float* __restrict__ dout) {
  const int b = blockIdx.x;
  const int t = threadIdx.x;
  const float* Bx = boxes + (size_t)b * NMSM * 4;
  const float* Sc = scores + (size_t)b * NMSM;
  float* Sw = swork + (size_t)b * NMSM;
  const float* Bo = boff + (size_t)b * NMSM * 4;
  const float* Ar = area + (size_t)b * NMSM;
  float* dets = dout + b * (DET_ * 5);
  float* labels = dout + B_ * DET_ * 5 + b * DET_;
  __shared__ float s_val[1024];
  __shared__ int s_idx[1024];
  __shared__ float s_box[4];
  __shared__ float s_area;
  __shared__ int s_ok;
  for (int it = 0; it < DET_; ++it) {
    float bv = -3.0e38f;
    int bi = 0;
    for (int j = t; j < NMSM; j += 1024) {
      float v = Sw[j];
      if (v > bv) { bv = v; bi = j; }
    }
    s_val[t] = bv;
    s_idx[t] = bi;
    __syncthreads();
    for (int off = 512; off > 0; off >>= 1) {
      if (t < off) {
        float v2 = s_val[t + off]; int i2 = s_idx[t + off];
        if (v2 > s_val[t] || (v2 == s_val[t] && i2 < s_idx[t])) { s_val[t] = v2; s_idx[t] = i2; }
      }
      __syncthreads();
    }
    if (t == 0) {
      int i = s_idx[0];
      int ok = (s_val[0] > NEGV * 0.5f) ? 1 : 0;
      s_ok = ok;
      if (ok) {
        dets[it * 5 + 0] = Bx[i * 4 + 0];
        dets[it * 5 + 1] = Bx[i * 4 + 1];
        dets[it * 5 + 2] = Bx[i * 4 + 2];
        dets[it * 5 + 3] = Bx[i * 4 + 3];
        dets[it * 5 + 4] = Sc[i];
        labels[it] = (float)(i % 90 + 1);
        s_box[0] = Bo[i * 4 + 0]; s_box[1] = Bo[i * 4 + 1];
        s_box[2] = Bo[i * 4 + 2]; s_box[3] = Bo[i * 4 + 3];
        s_area = Ar[i];
        Sw[i] = NEGV;
      }
    }
    __syncthreads();
    if (!s_ok) {
      for (int tt = it + t; tt < DET_; tt += 1024) {
        dets[tt * 5 + 0] = 0.0f; dets[tt * 5 + 1] = 0.0f; dets[tt * 5 + 2] = 0.0f;
        dets[tt * 5 + 3] = 0.0f; dets[tt * 5 + 4] = 0.0f;
        labels[tt] = -1.0f;
      }
      return;
    }
    const float bx1 = s_box[0], by1 = s_box[1], bx2 = s_box[2], by2 = s_box[3], ai = s_area;
    for (int j = t; j < NMSM; j += 1024) {
      float v = Sw[j];
      if (v <= NEGV * 0.5f) continue;
      float ix1 = fmaxf(bx1, Bo[j * 4 + 0]);
      float iy1 = fmaxf(by1, Bo[j * 4 + 1]);
      float ix2 = fminf(bx2, Bo[j * 4 + 2]);
      float iy2 = fminf(by2, Bo[j * 4 + 3]);
      float inter = fmaxf(ix2 - ix1, 0.0f) * fmaxf(iy2 - iy1, 0.0f);
      float iou = inter / (ai + Ar[j] - inter + 1e-9f);
      if (iou > 0.5f) Sw[j] = NEGV;
    }
    __syncthreads();
  }
}

// ---------------- launch ----------------
extern "C" void kernel_launch(void* const* d_in, const int* in_sizes, int n_in,
                              void* d_out, int out_size, void* d_ws, size_t ws_size,
                              hipStream_t stream) {
  const float* features  = (const float*)d_in[0];
  const float* proposals = (const float*)d_in[1];
  const float* w1   = (const float*)d_in[2];
  const float* b1   = (const float*)d_in[3];
  const float* w2   = (const float*)d_in[4];
  const float* b2   = (const float*)d_in[5];
  const float* wcls = (const float*)d_in[6];
  const float* bcls = (const float*)d_in[7];
  const float* wbb  = (const float*)d_in[8];
  const float* bbb  = (const float*)d_in[9];
  (void)in_sizes; (void)n_in; (void)out_size;

  char* p = (char*)d_ws;
  auto alloc = [&](size_t bytes) {
    char* r = p;
    p += (bytes + 255) & ~(size_t)255;
    return r;
  };
  bf16_t* A      = (bf16_t*)alloc((size_t)MPAD * DIN * 2);
  float*  ftbuf  = (float*)alloc((size_t)B_ * NPIX * C_ * 4);
  bf16_t* w1t    = (bf16_t*)alloc((size_t)REP_ * DIN * 2);
  bf16_t* w2t    = (bf16_t*)alloc((size_t)REP_ * REP_ * 2);
  bf16_t* wht    = (bf16_t*)alloc((size_t)HOUT * REP_ * 2);
  float*  biash  = (float*)alloc((size_t)HOUT * 4);
  bf16_t* h1     = (bf16_t*)alloc((size_t)MPAD * REP_ * 2);
  bf16_t* h2     = (bf16_t*)alloc((size_t)MPAD * REP_ * 2);
  float*  ho     = (float*)alloc((size_t)MPAD * HOUT * 4);
  float*  mxv    = (float*)alloc((size_t)M_ * 4);
  float*  invv   = (float*)alloc((size_t)M_ * 4);
  float*  boxes  = (float*)alloc((size_t)B_ * NMSM * 4 * 4);
  float*  scoresb= (float*)alloc((size_t)B_ * NMSM * 4);
  float*  sworkb = (float*)alloc((size_t)B_ * NMSM * 4);
  float*  boffb  = (float*)alloc((size_t)B_ * NMSM * 4 * 4);
  float*  areab  = (float*)alloc((size_t)B_ * NMSM * 4);

  size_t used = (size_t)(p - (char*)d_ws);
  size_t avail = (ws_size > used) ? (ws_size - used) : 0;
  bf16_t* partialH = (bf16_t*)p;   // bf16 partials (FC1/FC2)
  float*  partialF = (float*)p;    // f32 partials (FC3, stream-ordered reuse)
  const size_t chunkH = (size_t)MPAD * REP_ * 2;   // 4 MB
  const size_t chunkF = (size_t)MPAD * HOUT * 4;   // 4 MB
  int KC1 = 8;   // kLen = 1568, G = 49
  while (KC1 > 1 && (size_t)KC1 * chunkH > avail) KC1 >>= 1;
  int KC2 = 2;   // kLen = 512, G = 16; 256 blocks
  while (KC2 > 1 && (size_t)KC2 * chunkH > avail) KC2 >>= 1;
  int KC3 = 4;   // kLen = 256, G = 8; 256 blocks
  while (KC3 > 1 && (size_t)KC3 * chunkF > avail) KC3 >>= 1;

  // features -> channels-last (ft), then fused pre (roi reads ft; coalesced)
  ft_kernel<<<dim3((NPIX + 31) / 32, C_ / 32, B_), 256, 0, stream>>>(features, ftbuf);
  fused_pre_kernel<<<MPAD + NW1B + NW2B + NHWB + 1, 256, 0, stream>>>(
      ftbuf, proposals, w1, w2, wcls, wbb, bcls, bbb, A, w1t, w2t, wht, biash);

  // FC1: [2048 x 12544] @ [12544 x 1024] -> h1 (relu, bf16). 8-wave depth-3 pipeline.
  gemm8_kernel<<<32 * KC1, 512, 0, stream>>>(A, w1t, partialH, DIN, DIN / KC1, KC1);
  reduceH_kernel<<<(MPAD * REP_ / 8) / 256, 256, 0, stream>>>(partialH, b1, h1, KC1);
  // FC2: [2048 x 1024] @ [1024 x 1024] -> h2 (relu, bf16). 4-wave 128-tile pipeline, KC=2.
  gemm128_kernel<bf16_t><<<(MPAD / 128) * (REP_ / 128) * KC2, 256, 0, stream>>>(
      h1, w2t, partialH, REP_, REP_ / KC2, KC2, REP_ / 128, REP_);
  reduceH_kernel<<<(MPAD * REP_ / 8) / 256, 256, 0, stream>>>(partialH, b2, h2, KC2);
  // FC3 (heads): [2048 x 1024] @ [1024 x 512] -> ho (f32). 4-wave 128-tile pipeline, KC=4.
  gemm128_kernel<float><<<(MPAD / 128) * (HOUT / 128) * KC3, 256, 0, stream>>>(
      h2, wht, partialF, REP_, REP_ / KC3, KC3, HOUT / 128, HOUT);
  reduce_kernel<<<(MPAD * HOUT / 4) / 256, 256, 0, stream>>>(partialF, biash, ho, HOUT, KC3);

  rowsm_kernel<<<(M_ + 3) / 4, 256, 0, stream>>>(ho, mxv, invv);
  decode_kernel<<<(M_ * 90 + 255) / 256, 256, 0, stream>>>(ho, mxv, invv, proposals,
                                                           boxes, scoresb, sworkb, boffb, areab);
  nms_kernel<<<B_, 1024, 0, stream>>>(boxes, scoresb, sworkb, boffb, areab, (float*)d_out);
}

// Round 17
// 163.313 us; speedup vs baseline: 1.2955x; 1.0052x over previous
//
#include <hip/hip_runtime.h>
#include <stdint.h>

// ---------------- problem constants (hard-coded from reference) ----------------
#define B_    2
#define N_    1000
#define C_    256
#define H_    50
#define W_    50
#define P_    7
#define NCLS  91
#define REP_  1024
#define DIN   (C_ * P_ * P_)   // 12544
#define M_    (B_ * N_)        // 2000
#define MPAD  2048
#define HOUT  512              // padded head cols (91 cls + 364 bbox = 455 real)
#define DET_  100
#define NMSM  (N_ * 90)        // 90000 candidates per batch
#define NEGV  (-1000000000.0f)
#define SCALE_ 0.0625f
#define IMGF  800.0f
#define BBOX_CLIPF 4.135166556742356f  // log(1000/16)

#define NPIX  (H_ * W_)        // 2500
#define NW1B  ((DIN / 32) * (REP_ / 32))    // 12544
#define NW2B  ((REP_ / 32) * (REP_ / 32))   // 1024
#define NHWB  ((HOUT * REP_) / 256)         // 2048

typedef __bf16 bf16_t;
typedef __attribute__((ext_vector_type(8))) __bf16 bf16x8;
typedef __attribute__((ext_vector_type(4))) __bf16 bf16x4;
typedef __attribute__((ext_vector_type(4))) float f32x4;
typedef __attribute__((ext_vector_type(4))) int i32x4;

// async global->LDS, 16B per lane. LDS dest must be wave-uniform base (+lane*16 by HW).
__device__ __forceinline__ void gload16(const void* g, void* l) {
  auto gp = (const __attribute__((address_space(1))) uint32_t*)(uintptr_t)g;
  auto lp = (__attribute__((address_space(3))) uint32_t*)(uint32_t)(uintptr_t)l;
  __builtin_amdgcn_global_load_lds(gp, lp, 16, 0, 0);
}

// ---------------- features -> channels-last copy: ft[b][p][c] = features[b][c][p] ----------------
__global__ __launch_bounds__(256) void ft_kernel(const float* __restrict__ features,
                                                 float* __restrict__ ft) {
  __shared__ float tile[32][33];
  const int pb = blockIdx.x;
  const int cb = blockIdx.y;
  const int b  = blockIdx.z;
  const int p0 = pb * 32, c0 = cb * 32;
  const int tx = threadIdx.x & 31;
  const int ty = threadIdx.x >> 5;
  const float* in = features + (size_t)b * C_ * NPIX;
#pragma unroll
  for (int j = 0; j < 4; ++j) {
    int c = c0 + ty + j * 8;
    int p = p0 + tx;
    tile[ty + j * 8][tx] = (p < NPIX) ? in[(size_t)c * NPIX + p] : 0.0f;
  }
  __syncthreads();
  float* out = ft + (size_t)b * NPIX * C_;
#pragma unroll
  for (int j = 0; j < 4; ++j) {
    int p = p0 + ty + j * 8;
    int c = c0 + tx;
    if (p < NPIX) out[(size_t)p * C_ + c] = tile[tx][ty + j * 8];
  }
}

// ---------------- fused pre: ROI align (channels-last) + w^T transposes + head concat --------
__global__ __launch_bounds__(256) void fused_pre_kernel(const float* __restrict__ ft,
                                                        const float* __restrict__ proposals,
                                                        const float* __restrict__ w1,
                                                        const float* __restrict__ w2,
                                                        const float* __restrict__ wcls,
                                                        const float* __restrict__ wbb,
                                                        const float* __restrict__ bcls,
                                                        const float* __restrict__ bbb,
                                                        bf16_t* __restrict__ A,
                                                        bf16_t* __restrict__ w1t,
                                                        bf16_t* __restrict__ w2t,
                                                        bf16_t* __restrict__ wht,
                                                        float* __restrict__ biash) {
  __shared__ __align__(16) char smem[26656];
  int bidx = blockIdx.x;
  const int t = threadIdx.x;

  if (bidx < MPAD) {
    const int n = bidx;
    if (n >= M_) {
      f32x4 z = {0.f, 0.f, 0.f, 0.f};
      f32x4* arow = (f32x4*)(A + (size_t)n * DIN);
      for (int i = t; i < DIN / 8; i += 256) arow[i] = z;
      return;
    }
    int*   s_o = (int*)smem;                    // [49][4]
    float* s_w = (float*)(smem + 784);          // [49][4]
    bf16_t* sOut = (bf16_t*)(smem + 1568);      // [256][49]
    if (t < 49) {
      const int py = t / 7, px = t - (t / 7) * 7;
      const float* p = proposals + n * 4;
      float y1 = p[1] * SCALE_, y2 = p[3] * SCALE_;
      float bh = (y2 - y1) * (1.0f / 7.0f);
      float y = y1 + ((float)py + 0.5f) * bh - 0.5f;
      y = fminf(fmaxf(y, 0.0f), 49.0f);
      int y0 = (int)floorf(y);
      int dy = (y0 < 49) ? 1 : 0;
      float ly = y - (float)y0;
      float x1 = p[0] * SCALE_, x2 = p[2] * SCALE_;
      float bw = (x2 - x1) * (1.0f / 7.0f);
      float x = x1 + ((float)px + 0.5f) * bw - 0.5f;
      x = fminf(fmaxf(x, 0.0f), 49.0f);
      int x0 = (int)floorf(x);
      int dx = (x0 < 49) ? 1 : 0;
      float lx = x - (float)x0;
      const float hy = 1.0f - ly, hx = 1.0f - lx;
      int o00 = (y0 * W_ + x0) * C_;
      s_o[t * 4 + 0] = o00;
      s_o[t * 4 + 1] = o00 + dx * C_;
      s_o[t * 4 + 2] = o00 + dy * (W_ * C_);
      s_o[t * 4 + 3] = o00 + dy * (W_ * C_) + dx * C_;
      s_w[t * 4 + 0] = hy * hx;
      s_w[t * 4 + 1] = hy * lx;
      s_w[t * 4 + 2] = ly * hx;
      s_w[t * 4 + 3] = ly * lx;
    }
    __syncthreads();
    const int b = (n >= N_) ? 1 : 0;
    const float* fb = ft + (size_t)b * NPIX * C_;
    const int wv = t >> 6, l = t & 63;
    const int c4 = l * 4;
    for (int pp = wv; pp < 49; pp += 4) {
      const i32x4 o = *(const i32x4*)&s_o[pp * 4];
      const f32x4 wq = *(const f32x4*)&s_w[pp * 4];
      const f32x4 a00 = *(const f32x4*)(fb + o[0] + c4);
      const f32x4 a01 = *(const f32x4*)(fb + o[1] + c4);
      const f32x4 a10 = *(const f32x4*)(fb + o[2] + c4);
      const f32x4 a11 = *(const f32x4*)(fb + o[3] + c4);
      const f32x4 v = a00 * wq[0] + a01 * wq[1] + a10 * wq[2] + a11 * wq[3];
#pragma unroll
      for (int i = 0; i < 4; ++i) sOut[(c4 + i) * 49 + pp] = (bf16_t)v[i];
    }
    __syncthreads();
    f32x4* arow = (f32x4*)(A + (size_t)n * DIN);
    const f32x4* so = (const f32x4*)sOut;
    for (int i = t; i < DIN / 8; i += 256) arow[i] = so[i];
    return;
  }
  bidx -= MPAD;

  if (bidx < NW1B + NW2B) {
    float* tile = (float*)smem;  // [32][33]
    const float* in;
    bf16_t* out;
    int K, N, kbk, nbk;
    if (bidx < NW1B) {
      in = w1; out = w1t; K = DIN; N = REP_;
      kbk = bidx % (DIN / 32); nbk = bidx / (DIN / 32);
    } else {
      bidx -= NW1B;
      in = w2; out = w2t; K = REP_; N = REP_;
      kbk = bidx % (REP_ / 32); nbk = bidx / (REP_ / 32);
    }
    const int k0 = kbk * 32, n0 = nbk * 32;
    const int tx = t & 31;
    const int ty = t >> 5;
#pragma unroll
    for (int j = 0; j < 4; ++j) {
      int ky = ty + j * 8;
      tile[ky * 33 + tx] = in[(size_t)(k0 + ky) * N + n0 + tx];
    }
    __syncthreads();
    const int qx = t & 7;
    const int ny = t >> 3;
    bf16x4 o;
#pragma unroll
    for (int i = 0; i < 4; ++i) o[i] = (bf16_t)tile[(4 * qx + i) * 33 + ny];
    *(bf16x4*)(&out[(size_t)(n0 + ny) * K + k0 + 4 * qx]) = o;
  } else if (bidx < NW1B + NW2B + NHWB) {
    int idx = (bidx - NW1B - NW2B) * 256 + t;
    int j = idx >> 10;
    int k = idx & 1023;
    float v = 0.0f;
    if (j < NCLS) v = wcls[(size_t)k * NCLS + j];
    else if (j < 455) v = wbb[(size_t)k * 364 + (j - NCLS)];
    wht[idx] = (bf16_t)v;
  } else {
    for (int j = t; j < HOUT; j += 256) {
      float v = 0.0f;
      if (j < NCLS) v = bcls[j];
      else if (j < 455) v = bbb[j - NCLS];
      biash[j] = v;
    }
  }
}

// ---------------- FC1: 256x256-tile deep-pipelined MFMA GEMM (8-wave, split-K) ----------------
// R16 schedule + reads/MFMA in SAME scheduling region (compiler counted-lgkmcnt interleave:
// LDS pipe serves fragment reads DURING the MFMA cluster). Invariants: buf g data arrival
// via prev iter's vmcnt(8)+barrier; buf g overwrite (stage g+4, next iter) fenced by this
// iter's trailing lgkm(0)+barrier. Single barrier/K-tile, same vmcnt ladder, same VGPR count.
__global__ __launch_bounds__(512, 2) void gemm8_kernel(const bf16_t* __restrict__ A,
                                                       const bf16_t* __restrict__ Bt,
                                                       bf16_t* __restrict__ partial,
                                                       int K, int kLen, int KC) {
  __shared__ __align__(16) bf16_t lds[4 * 2 * 2 * 128 * 32];  // 128 KiB
  const int t = threadIdx.x;
  const int lane = t & 63;
  const int w = t >> 6;         // 0..7
  const int wm = w >> 2;        // 0..1
  const int wn = w & 3;         // 0..3
  const int bid = blockIdx.x;
  const int zc = bid % KC;
  const int inner = bid / KC;   // 0..31
  const int row0 = (inner >> 2) * 256;
  const int col0 = (inner & 3) * 256;
  const int kOff = zc * kLen;
  const int G = kLen >> 5;

  const int lr = lane & 15;
  const int kb = (lane >> 4) * 16;
  int aoff[8], boff[4];
#pragma unroll
  for (int m = 0; m < 8; ++m) {
    int r = m * 16 + lr;
    aoff[m] = (r * 64 + kb) ^ (((r >> 3) & 1) << 5);
  }
#pragma unroll
  for (int n = 0; n < 4; ++n) {
    int r = (wn & 1) * 64 + n * 16 + lr;
    boff[n] = (r * 64 + kb) ^ (((r >> 3) & 1) << 5);
  }

  const int s_row = t >> 2;
  const int s_k8 = (t & 3) ^ (((s_row >> 3) & 1) << 1);
  const bf16_t* pAs = A + (size_t)(row0 + s_row) * K + kOff + s_k8 * 8;
  const bf16_t* pBs = Bt + (size_t)(col0 + s_row) * K + kOff + s_k8 * 8;
  const size_t halfStride = (size_t)128 * K;
  char* ldsBase = (char*)&lds[0];
  const int wOff = w << 10;

  auto stage = [&](int buf, int hp, int kt) {
    const bf16_t* src = ((hp < 2) ? pAs : pBs) + (size_t)(hp & 1) * halfStride + kt * 32;
    char* dst = ldsBase + buf * 32768 + (hp >> 1) * 16384 + (hp & 1) * 8192 + wOff;
    gload16(src, dst);
  };

  f32x4 acc[8][4] = {};

#pragma unroll
  for (int hp = 0; hp < 4; ++hp) stage(0, hp, 0);
#pragma unroll
  for (int hp = 0; hp < 4; ++hp) stage(1, hp, 1);
#pragma unroll
  for (int hp = 0; hp < 4; ++hp) stage(2, hp, 2);
  asm volatile("s_waitcnt vmcnt(8)" ::: "memory");
  __builtin_amdgcn_s_barrier();
  __builtin_amdgcn_sched_barrier(0);

  for (int g = 0; g < G; ++g) {
    const int cb = g & 3;
    const int sb = (g + 3) & 3;
    const bool doStage = (g + 3) < G;
    if (doStage) {
#pragma unroll
      for (int hp = 0; hp < 4; ++hp) stage(sb, hp, g + 3);
    }
    if (doStage)          asm volatile("s_waitcnt vmcnt(8)" ::: "memory");  // kt g+1 landed
    else if (g == G - 3)  asm volatile("s_waitcnt vmcnt(4)" ::: "memory");
    else                  asm volatile("s_waitcnt vmcnt(0)" ::: "memory");
    // reads + MFMA in one region: compiler interleaves with counted lgkmcnt
    char* lA = ldsBase + cb * 32768 + wm * 8192;
    char* lB = ldsBase + cb * 32768 + 16384 + (wn >> 1) * 8192;
    bf16x8 af[8], bfv[4];
#pragma unroll
    for (int i = 0; i < 8; ++i) af[i] = *(const bf16x8*)(lA + aoff[i]);
#pragma unroll
    for (int j2 = 0; j2 < 4; ++j2) bfv[j2] = *(const bf16x8*)(lB + boff[j2]);
    __builtin_amdgcn_s_setprio(1);
#pragma unroll
    for (int i = 0; i < 8; ++i)
#pragma unroll
      for (int j2 = 0; j2 < 4; ++j2)
        acc[i][j2] = __builtin_amdgcn_mfma_f32_16x16x32_bf16(af[i], bfv[j2], acc[i][j2], 0, 0, 0);
    __builtin_amdgcn_s_setprio(0);
    asm volatile("s_waitcnt lgkmcnt(0)" ::: "memory");  // all my reads of buf cb retired
    __builtin_amdgcn_sched_barrier(0);
    __builtin_amdgcn_s_barrier();   // all waves done with buf cb; kt g+1 staged everywhere
    __builtin_amdgcn_sched_barrier(0);
  }

  bf16_t* out = partial + (size_t)zc * MPAD * REP_;
  const int crow = (lane >> 4) * 4;
#pragma unroll
  for (int n = 0; n < 4; ++n) {
    const int col = col0 + wn * 64 + n * 16 + lr;
#pragma unroll
    for (int m = 0; m < 8; ++m) {
      const int rowb = row0 + wm * 128 + m * 16 + crow;
#pragma unroll
      for (int j2 = 0; j2 < 4; ++j2)
        out[(size_t)(rowb + j2) * REP_ + col] = (bf16_t)acc[m][n][j2];
    }
  }
}

// ---------------- FC2/FC3: 128x128-tile deep-pipelined GEMM (4-wave, split-K) ----------------
// Same schedule transformation as gemm8 (reads+MFMA same region, trailing lgkm+barrier).
template <typename OT>
__global__ __launch_bounds__(256, 2) void gemm128_kernel(const bf16_t* __restrict__ A,
                                                         const bf16_t* __restrict__ Bt,
                                                         OT* __restrict__ partial,
                                                         int K, int kLen, int KC,
                                                         int GN, int ldc) {
  __shared__ __align__(16) bf16_t lds[4 * 2 * 128 * 32];  // 64 KiB
  const int t = threadIdx.x;
  const int lane = t & 63;
  const int w = t >> 6;         // 0..3
  const int wm = w >> 1;        // 0..1
  const int wn = w & 1;         // 0..1
  const int bid = blockIdx.x;
  const int zc = bid % KC;
  const int inner = bid / KC;
  const int row0 = (inner / GN) * 128;
  const int col0 = (inner % GN) * 128;
  const int kOff = zc * kLen;
  const int G = kLen >> 5;      // >= 3

  const int lr = lane & 15;
  const int kb = (lane >> 4) * 16;
  int aoff[4], boff[4];
#pragma unroll
  for (int m = 0; m < 4; ++m) {
    int r = wm * 64 + m * 16 + lr;
    aoff[m] = (r * 64 + kb) ^ (((r >> 3) & 1) << 5);
  }
#pragma unroll
  for (int n = 0; n < 4; ++n) {
    int r = wn * 64 + n * 16 + lr;
    boff[n] = (r * 64 + kb) ^ (((r >> 3) & 1) << 5);
  }

  const int s_row = t >> 2;
  const int s_k8 = (t & 3) ^ (((s_row >> 3) & 1) << 1);
  const bf16_t* pAs = A + (size_t)(row0 + s_row) * K + kOff + s_k8 * 8;
  const bf16_t* pBs = Bt + (size_t)(col0 + s_row) * K + kOff + s_k8 * 8;
  const size_t halfStride = (size_t)64 * K;
  char* ldsBase = (char*)&lds[0];
  const int wOff = w << 10;

  auto stage = [&](int buf, int hp, int kt) {
    const bf16_t* src = ((hp < 2) ? pAs : pBs) + (size_t)(hp & 1) * halfStride + kt * 32;
    char* dst = ldsBase + buf * 16384 + (hp >> 1) * 8192 + (hp & 1) * 4096 + wOff;
    gload16(src, dst);
  };

  f32x4 acc[4][4] = {};

#pragma unroll
  for (int hp = 0; hp < 4; ++hp) stage(0, hp, 0);
#pragma unroll
  for (int hp = 0; hp < 4; ++hp) stage(1, hp, 1);
#pragma unroll
  for (int hp = 0; hp < 4; ++hp) stage(2, hp, 2);
  asm volatile("s_waitcnt vmcnt(8)" ::: "memory");
  __builtin_amdgcn_s_barrier();
  __builtin_amdgcn_sched_barrier(0);

  for (int g = 0; g < G; ++g) {
    const int cb = g & 3;
    const int sb = (g + 3) & 3;
    const bool doStage = (g + 3) < G;
    if (doStage) {
#pragma unroll
      for (int hp = 0; hp < 4; ++hp) stage(sb, hp, g + 3);
    }
    if (doStage)          asm volatile("s_waitcnt vmcnt(8)" ::: "memory");
    else if (g == G - 3)  asm volatile("s_waitcnt vmcnt(4)" ::: "memory");
    else                  asm volatile("s_waitcnt vmcnt(0)" ::: "memory");
    char* lA = ldsBase + cb * 16384;
    char* lB = ldsBase + cb * 16384 + 8192;
    bf16x8 af[4], bfv[4];
#pragma unroll
    for (int i = 0; i < 4; ++i) af[i] = *(const bf16x8*)(lA + aoff[i]);
#pragma unroll
    for (int j2 = 0; j2 < 4; ++j2) bfv[j2] = *(const bf16x8*)(lB + boff[j2]);
    __builtin_amdgcn_s_setprio(1);
#pragma unroll
    for (int i = 0; i < 4; ++i)
#pragma unroll
      for (int j2 = 0; j2 < 4; ++j2)
        acc[i][j2] = __builtin_amdgcn_mfma_f32_16x16x32_bf16(af[i], bfv[j2], acc[i][j2], 0, 0, 0);
    __builtin_amdgcn_s_setprio(0);
    asm volatile("s_waitcnt lgkmcnt(0)" ::: "memory");
    __builtin_amdgcn_sched_barrier(0);
    __builtin_amdgcn_s_barrier();
    __builtin_amdgcn_sched_barrier(0);
  }

  OT* out = partial + (size_t)zc * MPAD * ldc;
  const int crow = (lane >> 4) * 4;
#pragma unroll
  for (int n = 0; n < 4; ++n) {
    const int col = col0 + wn * 64 + n * 16 + lr;
#pragma unroll
    for (int m = 0; m < 4; ++m) {
      const int rowb = row0 + wm * 64 + m * 16 + crow;
#pragma unroll
      for (int j2 = 0; j2 < 4; ++j2)
        out[(size_t)(rowb + j2) * ldc + col] = (OT)acc[m][n][j2];
    }
  }
}

// ---------------- bf16 split-K reduce: out = relu(sum + bias) -> bf16 (8/thread, ldc=REP_) ----
__global__ __launch_bounds__(256) void reduceH_kernel(const bf16_t* __restrict__ partial,
                                                      const float* __restrict__ bias,
                                                      bf16_t* __restrict__ out,
                                                      int KC) {
  const size_t idx8 = ((size_t)blockIdx.x * 256 + threadIdx.x) * 8;
  const size_t stride = (size_t)MPAD * REP_;
  float s[8] = {};
  for (int c = 0; c < KC; ++c) {
    const bf16x8 v = *(const bf16x8*)(partial + c * stride + idx8);
#pragma unroll
    for (int j = 0; j < 8; ++j) s[j] += (float)v[j];
  }
  const int col = (int)(idx8 & (size_t)(REP_ - 1));
  const f32x4 b0 = *(const f32x4*)(bias + col);
  const f32x4 b1 = *(const f32x4*)(bias + col + 4);
  bf16x8 o;
#pragma unroll
  for (int j = 0; j < 4; ++j) o[j] = (bf16_t)fmaxf(s[j] + b0[j], 0.0f);
#pragma unroll
  for (int j = 0; j < 4; ++j) o[4 + j] = (bf16_t)fmaxf(s[4 + j] + b1[j], 0.0f);
  *(bf16x8*)(out + idx8) = o;
}

// ---------------- f32 split-K reduce: out = sum + bias (f32) ----------------
__global__ __launch_bounds__(256) void reduce_kernel(const float* __restrict__ partial,
                                                     const float* __restrict__ bias,
                                                     float* __restrict__ out,
                                                     int ldc, int KC) {
  const size_t idx4 = ((size_t)blockIdx.x * 256 + threadIdx.x) * 4;
  f32x4 s = *(const f32x4*)(partial + idx4);
  const size_t stride = (size_t)MPAD * ldc;
  for (int c = 1; c < KC; ++c) s += *(const f32x4*)(partial + c * stride + idx4);
  const int col = (int)(idx4 & (size_t)(ldc - 1));
  s += *(const f32x4*)(bias + col);
  *(f32x4*)(out + idx4) = s;
}

// ---------------- row softmax stats: one wave per row ----------------
__global__ __launch_bounds__(256) void rowsm_kernel(const float* __restrict__ ho,
                                                    float* __restrict__ mxv,
                                                    float* __restrict__ invv) {
  const int row = blockIdx.x * 4 + (threadIdx.x >> 6);
  const int lane = threadIdx.x & 63;
  if (row >= M_) return;
  const float* r = ho + (size_t)row * HOUT;
  float v1 = (lane < NCLS) ? r[lane] : -3.0e38f;
  float v2 = (lane + 64 < NCLS) ? r[lane + 64] : -3.0e38f;
  float mx = fmaxf(v1, v2);
#pragma unroll
  for (int off = 32; off; off >>= 1) mx = fmaxf(mx, __shfl_xor(mx, off));
  float s = ((lane < NCLS) ? expf(v1 - mx) : 0.0f) + ((lane + 64 < NCLS) ? expf(v2 - mx) : 0.0f);
#pragma unroll
  for (int off = 32; off; off >>= 1) s += __shfl_xor(s, off);
  if (lane == 0) { mxv[row] = mx; invv[row] = 1.0f / s; }
}

// ---------------- decode + NMS prep: one thread per (roi, class) ----------------
__global__ __launch_bounds__(256) void decode_kernel(const float* __restrict__ ho,
                                                     const float* __restrict__ mxv,
                                                     const float* __restrict__ invv,
                                                     const float* __restrict__ props,
                                                     float* __restrict__ boxes,
                                                     float* __restrict__ scores,
                                                     float* __restrict__ swork,
                                                     float* __restrict__ boff,
                                                     float* __restrict__ area) {
  const int idx = blockIdx.x * 256 + threadIdx.x;
  if (idx >= M_ * 90) return;
  const int n = idx / 90;
  const int k = idx - n * 90 + 1;
  const float* row = ho + (size_t)n * HOUT;
  const float sc = expf(row[k] - mxv[n]) * invv[n];
  const float* p = props + n * 4;
  const float px1 = p[0], py1 = p[1], px2 = p[2], py2 = p[3];
  const float pw = px2 - px1, ph = py2 - py1;
  const float pcx = px1 + 0.5f * pw, pcy = py1 + 0.5f * ph;
  const float* d = row + NCLS + 4 * k;
  const float dx = d[0] * 0.1f;
  const float dy = d[1] * 0.1f;
  const float dw = fminf(d[2] * 0.2f, BBOX_CLIPF);
  const float dh = fminf(d[3] * 0.2f, BBOX_CLIPF);
  const float cx = dx * pw + pcx, cy = dy * ph + pcy;
  const float w = pw * expf(dw), h = ph * expf(dh);
  const float bx1 = fminf(fmaxf(cx - 0.5f * w, 0.0f), IMGF);
  const float by1 = fminf(fmaxf(cy - 0.5f * h, 0.0f), IMGF);
  const float bx2 = fminf(fmaxf(cx + 0.5f * w, 0.0f), IMGF);
  const float by2 = fminf(fmaxf(cy + 0.5f * h, 0.0f), IMGF);
  const int j = idx;
  boxes[4 * j + 0] = bx1; boxes[4 * j + 1] = by1;
  boxes[4 * j + 2] = bx2; boxes[4 * j + 3] = by2;
  scores[j] = sc;
  const float wv = bx2 - bx1, hv = by2 - by1;
  swork[j] = ((sc > 0.05f) && (wv >= 1.0f) && (hv >= 1.0f)) ? sc : NEGV;
  const float off = (float)k * (IMGF + 2.0f);
  const float ox1 = bx1 + off, oy1 = by1 + off, ox2 = bx2 + off, oy2 = by2 + off;
  boff[4 * j + 0] = ox1; boff[4 * j + 1] = oy1;
  boff[4 * j + 2] = ox2; boff[4 * j + 3] = oy2;
  area[j] = (ox2 - ox1) * (oy2 - oy1);
}

// ---------------- NMS: replicates jax.lax.scan semantics exactly ----------------
__global__ __launch_bounds__(1024) void nms_kernel(const float* __restrict__ boxes,
                                                   const float* __restrict__ scores,
                                                   float* __restrict__ swork,
                                                   const float* __restrict__ boff,
                                                   const float* __restrict__ area,
                                                   float* __restrict__ dout) {
  const int b = blockIdx.x;
  const int t = threadIdx.x;
  const float* Bx = boxes + (size_t)b * NMSM * 4;
  const float* Sc = scores + (size_t)b * NMSM;
  float* Sw = swork + (size_t)b * NMSM;
  const float* Bo = boff + (size_t)b * NMSM * 4;
  const float* Ar = area + (size_t)b * NMSM;
  float* dets = dout + b * (DET_ * 5);
  float* labels = dout + B_ * DET_ * 5 + b * DET_;
  __shared__ float s_val[1024];
  __shared__ int s_idx[1024];
  __shared__ float s_box[4];
  __shared__ float s_area;
  __shared__ int s_ok;
  for (int it = 0; it < DET_; ++it) {
    float bv = -3.0e38f;
    int bi = 0;
    for (int j = t; j < NMSM; j += 1024) {
      float v = Sw[j];
      if (v > bv) { bv = v; bi = j; }
    }
    s_val[t] = bv;
    s_idx[t] = bi;
    __syncthreads();
    for (int off = 512; off > 0; off >>= 1) {
      if (t < off) {
        float v2 = s_val[t + off]; int i2 = s_idx[t + off];
        if (v2 > s_val[t] || (v2 == s_val[t] && i2 < s_idx[t])) { s_val[t] = v2; s_idx[t] = i2; }
      }
      __syncthreads();
    }
    if (t == 0) {
      int i = s_idx[0];
      int ok = (s_val[0] > NEGV * 0.5f) ? 1 : 0;
      s_ok = ok;
      if (ok) {
        dets[it * 5 + 0] = Bx[i * 4 + 0];
        dets[it * 5 + 1] = Bx[i * 4 + 1];
        dets[it * 5 + 2] = Bx[i * 4 + 2];
        dets[it * 5 + 3] = Bx[i * 4 + 3];
        dets[it * 5 + 4] = Sc[i];
        labels[it] = (float)(i % 90 + 1);
        s_box[0] = Bo[i * 4 + 0]; s_box[1] = Bo[i * 4 + 1];
        s_box[2] = Bo[i * 4 + 2]; s_box[3] = Bo[i * 4 + 3];
        s_area = Ar[i];
        Sw[i] = NEGV;
      }
    }
    __syncthreads();
    if (!s_ok) {
      for (int tt = it + t; tt < DET_; tt += 1024) {
        dets[tt * 5 + 0] = 0.0f; dets[tt * 5 + 1] = 0.0f; dets[tt * 5 + 2] = 0.0f;
        dets[tt * 5 + 3] = 0.0f; dets[tt * 5 + 4] = 0.0f;
        labels[tt] = -1.0f;
      }
      return;
    }
    const float bx1 = s_box[0], by1 = s_box[1], bx2 = s_box[2], by2 = s_box[3], ai = s_area;
    for (int j = t; j < NMSM; j += 1024) {
      float v = Sw[j];
      if (v <= NEGV * 0.5f) continue;
      float ix1 = fmaxf(bx1, Bo[j * 4 + 0]);
      float iy1 = fmaxf(by1, Bo[j * 4 + 1]);
      float ix2 = fminf(bx2, Bo[j * 4 + 2]);
      float iy2 = fminf(by2, Bo[j * 4 + 3]);
      float inter = fmaxf(ix2 - ix1, 0.0f) * fmaxf(iy2 - iy1, 0.0f);
      float iou = inter / (ai + Ar[j] - inter + 1e-9f);
      if (iou > 0.5f) Sw[j] = NEGV;
    }
    __syncthreads();
  }
}

// ---------------- launch ----------------
extern "C" void kernel_launch(void* const* d_in, const int* in_sizes, int n_in,
                              void* d_out, int out_size, void* d_ws, size_t ws_size,
                              hipStream_t stream) {
  const float* features  = (const float*)d_in[0];
  const float* proposals = (const float*)d_in[1];
  const float* w1   = (const float*)d_in[2];
  const float* b1   = (const float*)d_in[3];
  const float* w2   = (const float*)d_in[4];
  const float* b2   = (const float*)d_in[5];
  const float* wcls = (const float*)d_in[6];
  const float* bcls = (const float*)d_in[7];
  const float* wbb  = (const float*)d_in[8];
  const float* bbb  = (const float*)d_in[9];
  (void)in_sizes; (void)n_in; (void)out_size;

  char* p = (char*)d_ws;
  auto alloc = [&](size_t bytes) {
    char* r = p;
    p += (bytes + 255) & ~(size_t)255;
    return r;
  };
  bf16_t* A      = (bf16_t*)alloc((size_t)MPAD * DIN * 2);
  float*  ftbuf  = (float*)alloc((size_t)B_ * NPIX * C_ * 4);
  bf16_t* w1t    = (bf16_t*)alloc((size_t)REP_ * DIN * 2);
  bf16_t* w2t    = (bf16_t*)alloc((size_t)REP_ * REP_ * 2);
  bf16_t* wht    = (bf16_t*)alloc((size_t)HOUT * REP_ * 2);
  float*  biash  = (float*)alloc((size_t)HOUT * 4);
  bf16_t* h1     = (bf16_t*)alloc((size_t)MPAD * REP_ * 2);
  bf16_t* h2     = (bf16_t*)alloc((size_t)MPAD * REP_ * 2);
  float*  ho     = (float*)alloc((size_t)MPAD * HOUT * 4);
  float*  mxv    = (float*)alloc((size_t)M_ * 4);
  float*  invv   = (float*)alloc((size_t)M_ * 4);
  float*  boxes  = (float*)alloc((size_t)B_ * NMSM * 4 * 4);
  float*  scoresb= (float*)alloc((size_t)B_ * NMSM * 4);
  float*  sworkb = (float*)alloc((size_t)B_ * NMSM * 4);
  float*  boffb  = (float*)alloc((size_t)B_ * NMSM * 4 * 4);
  float*  areab  = (float*)alloc((size_t)B_ * NMSM * 4);

  size_t used = (size_t)(p - (char*)d_ws);
  size_t avail = (ws_size > used) ? (ws_size - used) : 0;
  bf16_t* partialH = (bf16_t*)p;   // bf16 partials (FC1/FC2)
  float*  partialF = (float*)p;    // f32 partials (FC3, stream-ordered reuse)
  const size_t chunkH = (size_t)MPAD * REP_ * 2;   // 4 MB
  const size_t chunkF = (size_t)MPAD * HOUT * 4;   // 4 MB
  int KC1 = 8;   // kLen = 1568, G = 49
  while (KC1 > 1 && (size_t)KC1 * chunkH > avail) KC1 >>= 1;
  int KC2 = 2;   // kLen = 512, G = 16; 256 blocks
  while (KC2 > 1 && (size_t)KC2 * chunkH > avail) KC2 >>= 1;
  int KC3 = 4;   // kLen = 256, G = 8; 256 blocks
  while (KC3 > 1 && (size_t)KC3 * chunkF > avail) KC3 >>= 1;

  ft_kernel<<<dim3((NPIX + 31) / 32, C_ / 32, B_), 256, 0, stream>>>(features, ftbuf);
  fused_pre_kernel<<<MPAD + NW1B + NW2B + NHWB + 1, 256, 0, stream>>>(
      ftbuf, proposals, w1, w2, wcls, wbb, bcls, bbb, A, w1t, w2t, wht, biash);

  // FC1: [2048 x 12544] @ [12544 x 1024] -> h1 (relu, bf16). 8-wave depth-3 pipeline.
  gemm8_kernel<<<32 * KC1, 512, 0, stream>>>(A, w1t, partialH, DIN, DIN / KC1, KC1);
  reduceH_kernel<<<(MPAD * REP_ / 8) / 256, 256, 0, stream>>>(partialH, b1, h1, KC1);
  // FC2: [2048 x 1024] @ [1024 x 1024] -> h2 (relu, bf16). 4-wave 128-tile pipeline, KC=2.
  gemm128_kernel<bf16_t><<<(MPAD / 128) * (REP_ / 128) * KC2, 256, 0, stream>>>(
      h1, w2t, partialH, REP_, REP_ / KC2, KC2, REP_ / 128, REP_);
  reduceH_kernel<<<(MPAD * REP_ / 8) / 256, 256, 0, stream>>>(partialH, b2, h2, KC2);
  // FC3 (heads): [2048 x 1024] @ [1024 x 512] -> ho (f32). 4-wave 128-tile pipeline, KC=4.
  gemm128_kernel<float><<<(MPAD / 128) * (HOUT / 128) * KC3, 256, 0, stream>>>(
      h2, wht, partialF, REP_, REP_ / KC3, KC3, HOUT / 128, HOUT);
  reduce_kernel<<<(MPAD * HOUT / 4) / 256, 256, 0, stream>>>(partialF, biash, ho, HOUT, KC3);

  rowsm_kernel<<<(M_ + 3) / 4, 256, 0, stream>>>(ho, mxv, invv);
  decode_kernel<<<(M_ * 90 + 255) / 256, 256, 0, stream>>>(ho, mxv, invv, proposals,
                                                           boxes, scoresb, sworkb, boffb, areab);
  nms_kernel<<<B_, 1024, 0, stream>>>(boxes, scoresb, sworkb, boffb, areab, (float*)d_out);
}